// Round 8
// baseline (789.807 us; speedup 1.0000x reference)
//
#include <hip/hip_runtime.h>
#include <stdint.h>

#define D_IN 1024
#define C1   1024   // H1*HID
#define C2   256    // H2*HID
#define NEG  0.2f

typedef unsigned int u32;
typedef uint16_t u16;
typedef __attribute__((ext_vector_type(8))) short bf16x8;
typedef __attribute__((ext_vector_type(4))) float f32x4;

__device__ __forceinline__ float bf2f(u32 lo16) { return __uint_as_float(lo16 << 16); }
__device__ __forceinline__ u16 f2bf(float f) {
  u32 u = __float_as_uint(f);
  u += 0x7fffu + ((u >> 16) & 1u);   // RNE
  return (u16)(u >> 16);
}
__device__ __forceinline__ u32 cvtpk_bf16(float lo, float hi) {
  u32 d;
  asm("v_cvt_pk_bf16_f32 %0, %1, %2" : "=v"(d) : "v"(lo), "v"(hi));
  return d;
}

__device__ __forceinline__ void gload16(const u16* g, u16* l) {
  __builtin_amdgcn_global_load_lds(
      (const __attribute__((address_space(1))) unsigned int*)g,
      (__attribute__((address_space(3))) unsigned int*)l,
      16, 0, 0);
}

// ---------------- transpose+cast W [K][Nc] f32 -> Wt [Nc][K] bf16 ------------
__global__ void transpose_cast_k(const float* __restrict__ W, u16* __restrict__ Wt,
                                 int K, int Nc) {
  __shared__ float sh[32][33];
  int k0 = blockIdx.x * 32, n0 = blockIdx.y * 32;
  int tx = threadIdx.x, ty = threadIdx.y;  // block (32,8)
#pragma unroll
  for (int i = 0; i < 32; i += 8)
    sh[ty + i][tx] = W[(long long)(k0 + ty + i) * Nc + (n0 + tx)];
  __syncthreads();
#pragma unroll
  for (int i = 0; i < 32; i += 8)
    Wt[(long long)(n0 + ty + i) * K + (k0 + tx)] = f2bf(sh[tx][ty + i]);
}

// ---------------- concat two bias vectors -----------------------------------
__global__ void concat_bias_k(const float* __restrict__ a, const float* __restrict__ b,
                              float* __restrict__ o, int na, int nb) {
  int i = blockIdx.x * 256 + threadIdx.x;
  if (i < na) o[i] = a[i];
  else if (i < na + nb) o[i] = b[i - na];
}

// ============ 256x256 BK=64 8-wave phase-interleaved MFMA GEMM ===============
// r4 schedule (best measured: 288us).  F32A=false: bf16 A via global_load_lds,
// stage slots ph1:A1(t+1) ph2:B0(t+1) ph3:B1(t+1) ph4:A0(t+2), vmcnt(2)/tile.
// F32A=true: A read as f32 + v_cvt_pk_bf16_f32 + ds_write (kills cast_x);
// loads issued at phase top (>=350cy lead), written after MFMA; B via
// gload_lds at t+2 in ph3/ph4, tile-end vmcnt(4).  Source pre-swizzle +
// linear LDS dest unchanged (rule #21).
template <int TN, bool F32A>
__global__ __launch_bounds__(512, 2) void gemm8_k(
    const void* __restrict__ Ap, const u16* __restrict__ Bt,
    const float* __restrict__ bias, u16* __restrict__ C, int K, int NR) {
  const u16*   Ab = (const u16*)Ap;
  const float* Af = (const float*)Ap;
  __shared__ u16 As[2][2][8192];
  __shared__ u16 Bs[2][2][8192];
  const int nx = gridDim.x, ny = gridDim.y;
  const int nwg = nx * ny;
  int id = blockIdx.y * nx + blockIdx.x;
  int q = nwg >> 3, r = nwg & 7;
  int xcd = id & 7, loc = id >> 3;
  int sid = (xcd < r ? xcd * (q + 1) : r * (q + 1) + (xcd - r) * q) + loc;
  const int m0 = (sid / ny) * 256;   // n varies fastest within an XCD
  const int n0 = (sid % ny) * 256;

  const int tid = threadIdx.x;
  const int lane = tid & 63;
  const int wave = tid >> 6;
  const int wm = wave >> 2;          // 0..1  (A half)
  const int wn = wave & 3;           // 0..3
  const int bh = wn >> 1;            // B half this wave reads
  const int bql = (wn & 1) * 2048;   // B quarter offset within half (u16)

  const int srow = tid >> 2;         // staging row 0..127
  const int kq   = tid & 3;          // physical k-chunk
  const int ksw  = (kq ^ ((srow >> 1) & 3)) * 8;  // swizzled src col (elems)

  const int nt = K / 64;

  const u16* gA[2];
  const float* gAf[2];
  if constexpr (F32A) {
    int r0 = m0 + srow;       if (r0 >= NR) r0 = NR - 1;
    int r1 = m0 + 128 + srow; if (r1 >= NR) r1 = NR - 1;
    gAf[0] = Af + (long long)r0 * K + ksw;
    gAf[1] = Af + (long long)r1 * K + ksw;
  } else {
    gA[0] = Ab + (long long)(m0 + srow) * K + ksw;
    gA[1] = Ab + (long long)(m0 + 128 + srow) * K + ksw;
  }
  const u16* gB[2] = { Bt + (long long)(n0 + srow) * K + ksw,
                       Bt + (long long)(n0 + 128 + srow) * K + ksw };

  auto stageA = [&](int kt, int h) {
    if constexpr (!F32A) {
      int db = kt & 1;
      gload16(gA[h] + kt * 64,      &As[db][h][tid * 8]);
      gload16(gA[h] + kt * 64 + 32, &As[db][h][4096 + tid * 8]);
    }
  };
  auto stageB = [&](int kt, int h) {
    int db = kt & 1;
    gload16(gB[h] + kt * 64,      &Bs[db][h][tid * 8]);
    gload16(gB[h] + kt * 64 + 32, &Bs[db][h][4096 + tid * 8]);
  };

  float4 afv[4];
  auto loadAf = [&](int kt, int h) {
    if constexpr (F32A) {
      const float* s = gAf[h] + kt * 64;
      afv[0] = *(const float4*)(s);
      afv[1] = *(const float4*)(s + 4);
      afv[2] = *(const float4*)(s + 32);
      afv[3] = *(const float4*)(s + 36);
    }
  };
  auto writeAf = [&](int kt, int h) {
    if constexpr (F32A) {
      int db = kt & 1;
      uint4 w0, w1;
      w0.x = cvtpk_bf16(afv[0].x, afv[0].y); w0.y = cvtpk_bf16(afv[0].z, afv[0].w);
      w0.z = cvtpk_bf16(afv[1].x, afv[1].y); w0.w = cvtpk_bf16(afv[1].z, afv[1].w);
      w1.x = cvtpk_bf16(afv[2].x, afv[2].y); w1.y = cvtpk_bf16(afv[2].z, afv[2].w);
      w1.z = cvtpk_bf16(afv[3].x, afv[3].y); w1.w = cvtpk_bf16(afv[3].z, afv[3].w);
      *(uint4*)(&As[db][h][tid * 8]) = w0;
      *(uint4*)(&As[db][h][4096 + tid * 8]) = w1;
    }
  };

  // fragment read base: frow*32 + physchunk*8 (u16), physchunk = lq ^ s(frow)
  const int rbase = (lane & 15) * 32 + (((lane >> 4) ^ ((lane >> 1) & 3)) << 3);

  f32x4 acc[8][4] = {};
  bf16x8 av[4][2], bv[4][2];

  // ---- prologue ----
  if constexpr (F32A) {
    loadAf(0, 0);
    stageB(0, 0); stageB(0, 1);
    writeAf(0, 0);
    loadAf(0, 1);
    if (nt > 1) { stageB(1, 0); stageB(1, 1); }
    writeAf(0, 1);
    asm volatile("s_waitcnt lgkmcnt(0)" ::: "memory");
    if (nt > 1) {
      asm volatile("s_waitcnt vmcnt(4)" ::: "memory");
    } else {
      asm volatile("s_waitcnt vmcnt(0)" ::: "memory");
    }
  } else {
    stageA(0, 0); stageA(0, 1); stageB(0, 0); stageB(0, 1);
    if (nt > 1) {
      stageA(1, 0);
      asm volatile("s_waitcnt vmcnt(2)" ::: "memory");
    } else {
      asm volatile("s_waitcnt vmcnt(0)" ::: "memory");
    }
  }
  __builtin_amdgcn_s_barrier();

  for (int t = 0; t < nt; ++t) {
    const int cur = t & 1;
    const u16* Al = &As[cur][wm][0];
    const u16* Bl = &Bs[cur][bh][0];

    // ---- phase 1: Q1 (m 0..3, n 0..1) ----
    if (F32A && t + 1 < nt) loadAf(t + 1, 0);
#pragma unroll
    for (int i = 0; i < 4; ++i) {
      av[i][0] = *(const bf16x8*)(Al + i * 512 + rbase);
      av[i][1] = *(const bf16x8*)(Al + 4096 + i * 512 + rbase);
    }
#pragma unroll
    for (int j = 0; j < 2; ++j) {
      bv[j][0] = *(const bf16x8*)(Bl + bql + j * 512 + rbase);
      bv[j][1] = *(const bf16x8*)(Bl + 4096 + bql + j * 512 + rbase);
    }
    if (!F32A && t + 1 < nt) stageA(t + 1, 1);
    __builtin_amdgcn_s_barrier();
    __builtin_amdgcn_s_setprio(1);
#pragma unroll
    for (int i = 0; i < 4; ++i)
#pragma unroll
      for (int j = 0; j < 2; ++j) {
        acc[i][j] = __builtin_amdgcn_mfma_f32_16x16x32_bf16(av[i][0], bv[j][0], acc[i][j], 0, 0, 0);
        acc[i][j] = __builtin_amdgcn_mfma_f32_16x16x32_bf16(av[i][1], bv[j][1], acc[i][j], 0, 0, 0);
      }
    __builtin_amdgcn_s_setprio(0);
    if (F32A && t + 1 < nt) {
      writeAf(t + 1, 0);
      asm volatile("s_waitcnt lgkmcnt(0)" ::: "memory");
    }
    __builtin_amdgcn_s_barrier();

    // ---- phase 2: Q2 (m 0..3, n 2..3) ----
    if (F32A && t + 1 < nt) loadAf(t + 1, 1);
#pragma unroll
    for (int j = 2; j < 4; ++j) {
      bv[j][0] = *(const bf16x8*)(Bl + bql + j * 512 + rbase);
      bv[j][1] = *(const bf16x8*)(Bl + 4096 + bql + j * 512 + rbase);
    }
    if (!F32A && t + 1 < nt) stageB(t + 1, 0);
    __builtin_amdgcn_s_barrier();
    __builtin_amdgcn_s_setprio(1);
#pragma unroll
    for (int i = 0; i < 4; ++i)
#pragma unroll
      for (int j = 2; j < 4; ++j) {
        acc[i][j] = __builtin_amdgcn_mfma_f32_16x16x32_bf16(av[i][0], bv[j][0], acc[i][j], 0, 0, 0);
        acc[i][j] = __builtin_amdgcn_mfma_f32_16x16x32_bf16(av[i][1], bv[j][1], acc[i][j], 0, 0, 0);
      }
    __builtin_amdgcn_s_setprio(0);
    if (F32A && t + 1 < nt) {
      writeAf(t + 1, 1);
      asm volatile("s_waitcnt lgkmcnt(0)" ::: "memory");
    }
    __builtin_amdgcn_s_barrier();

    // ---- phase 3: Q3 (m 4..7, n 2..3) ----
    if (F32A && t + 2 < nt) stageB(t + 2, 0);
#pragma unroll
    for (int i = 0; i < 4; ++i) {
      av[i][0] = *(const bf16x8*)(Al + (4 + i) * 512 + rbase);
      av[i][1] = *(const bf16x8*)(Al + 4096 + (4 + i) * 512 + rbase);
    }
    if (!F32A && t + 1 < nt) stageB(t + 1, 1);
    __builtin_amdgcn_s_barrier();
    __builtin_amdgcn_s_setprio(1);
#pragma unroll
    for (int i = 0; i < 4; ++i)
#pragma unroll
      for (int j = 2; j < 4; ++j) {
        acc[4 + i][j] = __builtin_amdgcn_mfma_f32_16x16x32_bf16(av[i][0], bv[j][0], acc[4 + i][j], 0, 0, 0);
        acc[4 + i][j] = __builtin_amdgcn_mfma_f32_16x16x32_bf16(av[i][1], bv[j][1], acc[4 + i][j], 0, 0, 0);
      }
    __builtin_amdgcn_s_setprio(0);
    __builtin_amdgcn_s_barrier();

    // ---- phase 4: Q4 (m 4..7, n 0..1) ----
    if (F32A) {
      if (t + 2 < nt) stageB(t + 2, 1);
    } else {
      if (t + 2 < nt) stageA(t + 2, 0);
    }
    __builtin_amdgcn_s_barrier();
    __builtin_amdgcn_s_setprio(1);
#pragma unroll
    for (int i = 0; i < 4; ++i)
#pragma unroll
      for (int j = 0; j < 2; ++j) {
        acc[4 + i][j] = __builtin_amdgcn_mfma_f32_16x16x32_bf16(av[i][0], bv[j][0], acc[4 + i][j], 0, 0, 0);
        acc[4 + i][j] = __builtin_amdgcn_mfma_f32_16x16x32_bf16(av[i][1], bv[j][1], acc[4 + i][j], 0, 0, 0);
      }
    __builtin_amdgcn_s_setprio(0);
    if (t + 2 < nt) {
      if (F32A) {
        asm volatile("s_waitcnt vmcnt(4)" ::: "memory");  // B(t+2) in flight
      } else {
        asm volatile("s_waitcnt vmcnt(2)" ::: "memory");  // A0(t+2) in flight
      }
    } else if (t + 1 < nt) {
      asm volatile("s_waitcnt vmcnt(0)" ::: "memory");    // tail drain
    }
    __builtin_amdgcn_s_barrier();
  }

  // ---- epilogue: D mapping col=lane&15, row=(lane>>4)*4+j ----
#pragma unroll
  for (int mf = 0; mf < 8; ++mf) {
    int r0 = m0 + wm * 128 + mf * 16 + ((lane >> 4) << 2);
#pragma unroll
    for (int nf = 0; nf < 4; ++nf) {
      int c = n0 + wn * 64 + nf * 16 + (lane & 15);
      float b = bias[c];
#pragma unroll
      for (int j = 0; j < 4; ++j)
        C[(long long)(r0 + j) * TN + c] = f2bf(acc[mf][nf][j] + b);
    }
  }
}

// ---------------- CSR build (by dst) ----------------------------------------
__global__ void count_k(const int* __restrict__ ei, int* __restrict__ counts,
                        int E0, int E) {
  for (int e = blockIdx.x * blockDim.x + threadIdx.x; e < E;
       e += gridDim.x * blockDim.x) {
    int dst = (e < E0) ? ei[E0 + e] : e - E0;
    atomicAdd(&counts[dst], 1);
  }
}

__global__ void blocksum_k(const int* __restrict__ counts, int* __restrict__ bsum, int n) {
  int i = blockIdx.x * 256 + threadIdx.x;
  int v = (i < n) ? counts[i] : 0;
#pragma unroll
  for (int off = 1; off < 64; off <<= 1) v += __shfl_xor(v, off);
  __shared__ int sh[4];
  if ((threadIdx.x & 63) == 0) sh[threadIdx.x >> 6] = v;
  __syncthreads();
  if (threadIdx.x == 0) bsum[blockIdx.x] = sh[0] + sh[1] + sh[2] + sh[3];
}

__global__ void scanb_k(const int* __restrict__ bsum, int* __restrict__ boff,
                        int nb, int* __restrict__ indptr, int n, int E) {
  __shared__ int sh[256];
  int i = threadIdx.x;
  int v = (i < nb) ? bsum[i] : 0;
  sh[i] = v;
  __syncthreads();
  int sum = v;
  for (int off = 1; off < 256; off <<= 1) {
    int t = (i >= off) ? sh[i - off] : 0;
    __syncthreads();
    sum += t;
    sh[i] = sum;
    __syncthreads();
  }
  if (i < nb) boff[i] = sum - v;  // exclusive
  if (i == 0) indptr[n] = E;
}

__global__ void scanf_k(const int* __restrict__ counts, const int* __restrict__ boff,
                        int* __restrict__ indptr, int n) {
  __shared__ int sh[256];
  int b = blockIdx.x;
  int i = b * 256 + threadIdx.x;
  int v = (i < n) ? counts[i] : 0;
  sh[threadIdx.x] = v;
  __syncthreads();
  int sum = v;
  for (int off = 1; off < 256; off <<= 1) {
    int t = (threadIdx.x >= off) ? sh[threadIdx.x - off] : 0;
    __syncthreads();
    sum += t;
    sh[threadIdx.x] = sum;
    __syncthreads();
  }
  if (i < n) indptr[i] = boff[b] + sum - v;
}

// store SRC id (not edge id) in CSR order
__global__ void scatter_k(const int* __restrict__ ei, const int* __restrict__ indptr,
                          int* __restrict__ cursor, int* __restrict__ esrc,
                          int E0, int E) {
  for (int e = blockIdx.x * blockDim.x + threadIdx.x; e < E;
       e += gridDim.x * blockDim.x) {
    int dst, src;
    if (e < E0) { src = ei[e]; dst = ei[E0 + e]; } else { src = dst = e - E0; }
    int pos = atomicAdd(&cursor[dst], 1);
    esrc[indptr[dst] + pos] = src;
  }
}

// ---------------- fused edge layer 1 (H=4): alpha+softmax+agg, online --------
__global__ __launch_bounds__(256) void fused_edge1_k(
    const u16* __restrict__ XLR, const int* __restrict__ indptr,
    const int* __restrict__ esrc, const float* __restrict__ att,
    const float* __restrict__ bias, u16* __restrict__ X2, int N) {
  int d = blockIdx.x;
  int tid = threadIdx.x;
  int c0 = tid * 4;  // channel in [0,1024); head = tid>>6
  if (d >= N) {
    *(ushort4*)(X2 + (long long)d * C1 + c0) = make_ushort4(0, 0, 0, 0);
    return;
  }
  ushort4 xr4 = *(const ushort4*)(XLR + (long long)d * 2048 + 1024 + c0);
  float xr0 = bf2f(xr4.x), xr1 = bf2f(xr4.y), xr2 = bf2f(xr4.z), xr3 = bf2f(xr4.w);
  float4 at = *(const float4*)(att + c0);

  float m = -INFINITY, l = 0.f;
  float a0 = 0.f, a1 = 0.f, a2 = 0.f, a3 = 0.f;
  int p = indptr[d], pend = indptr[d + 1];
  ushort4 z4 = make_ushort4(0, 0, 0, 0);
#define LD1(ix) (*(const ushort4*)(XLR + (long long)esrc[ix] * 2048 + c0))
  ushort4 qa = (p < pend) ? LD1(p) : z4;
  ushort4 qb = (p + 1 < pend) ? LD1(p + 1) : z4;
  ushort4 ra = (p + 2 < pend) ? LD1(p + 2) : z4;
  ushort4 rb = (p + 3 < pend) ? LD1(p + 3) : z4;
  int i = p;
  for (; i + 1 < pend; i += 2) {
    ushort4 ca = qa, cb = qb;
    qa = ra; qb = rb;
    ra = (i + 4 < pend) ? LD1(i + 4) : z4;
    rb = (i + 5 < pend) ? LD1(i + 5) : z4;
    float xa0 = bf2f(ca.x), xa1 = bf2f(ca.y), xa2 = bf2f(ca.z), xa3 = bf2f(ca.w);
    float xb0 = bf2f(cb.x), xb1 = bf2f(cb.y), xb2 = bf2f(cb.z), xb3 = bf2f(cb.w);
    float ta0 = xa0 + xr0, ta1 = xa1 + xr1, ta2 = xa2 + xr2, ta3 = xa3 + xr3;
    float tb0 = xb0 + xr0, tb1 = xb1 + xr1, tb2 = xb2 + xr2, tb3 = xb3 + xr3;
    ta0 = ta0 > 0.f ? ta0 : NEG * ta0;  ta1 = ta1 > 0.f ? ta1 : NEG * ta1;
    ta2 = ta2 > 0.f ? ta2 : NEG * ta2;  ta3 = ta3 > 0.f ? ta3 : NEG * ta3;
    tb0 = tb0 > 0.f ? tb0 : NEG * tb0;  tb1 = tb1 > 0.f ? tb1 : NEG * tb1;
    tb2 = tb2 > 0.f ? tb2 : NEG * tb2;  tb3 = tb3 > 0.f ? tb3 : NEG * tb3;
    float sa = at.x * ta0 + at.y * ta1 + at.z * ta2 + at.w * ta3;
    float sb = at.x * tb0 + at.y * tb1 + at.z * tb2 + at.w * tb3;
#pragma unroll
    for (int off = 1; off < 64; off <<= 1) {
      sa += __shfl_xor(sa, off);
      sb += __shfl_xor(sb, off);
    }
    float mnew = fmaxf(fmaxf(m, sa), sb);
    float scale = __expf(m - mnew);
    float wa = __expf(sa - mnew);
    float wb = __expf(sb - mnew);
    l = l * scale + wa + wb;
    a0 = a0 * scale + wa * xa0 + wb * xb0;
    a1 = a1 * scale + wa * xa1 + wb * xb1;
    a2 = a2 * scale + wa * xa2 + wb * xb2;
    a3 = a3 * scale + wa * xa3 + wb * xb3;
    m = mnew;
  }
  if (i < pend) {  // tail single edge (data in qa)
    float xa0 = bf2f(qa.x), xa1 = bf2f(qa.y), xa2 = bf2f(qa.z), xa3 = bf2f(qa.w);
    float ta0 = xa0 + xr0, ta1 = xa1 + xr1, ta2 = xa2 + xr2, ta3 = xa3 + xr3;
    ta0 = ta0 > 0.f ? ta0 : NEG * ta0;  ta1 = ta1 > 0.f ? ta1 : NEG * ta1;
    ta2 = ta2 > 0.f ? ta2 : NEG * ta2;  ta3 = ta3 > 0.f ? ta3 : NEG * ta3;
    float sa = at.x * ta0 + at.y * ta1 + at.z * ta2 + at.w * ta3;
#pragma unroll
    for (int off = 1; off < 64; off <<= 1) sa += __shfl_xor(sa, off);
    float mnew = fmaxf(m, sa);
    float scale = __expf(m - mnew);
    float wa = __expf(sa - mnew);
    l = l * scale + wa;
    a0 = a0 * scale + wa * xa0;
    a1 = a1 * scale + wa * xa1;
    a2 = a2 * scale + wa * xa2;
    a3 = a3 * scale + wa * xa3;
  }
#undef LD1
  float inv = 1.f / (l + 1e-16f);
  float4 b = *(const float4*)(bias + c0);
  ushort4 o;
  o.x = f2bf(fmaxf(a0 * inv + b.x, 0.f));
  o.y = f2bf(fmaxf(a1 * inv + b.y, 0.f));
  o.z = f2bf(fmaxf(a2 * inv + b.z, 0.f));
  o.w = f2bf(fmaxf(a3 * inv + b.w, 0.f));
  *(ushort4*)(X2 + (long long)d * C1 + c0) = o;
}

// ---------------- fused edge layer 2 (H=1): one wave per dst, f32 out --------
__global__ __launch_bounds__(256) void fused_edge2_k(
    const u16* __restrict__ XLR, const int* __restrict__ indptr,
    const int* __restrict__ esrc, const float* __restrict__ att,
    const float* __restrict__ bias, float* __restrict__ out, int N) {
  int d = blockIdx.x * 4 + (threadIdx.x >> 6);
  if (d >= N) return;
  int lane = threadIdx.x & 63;
  int c0 = lane * 4;
  ushort4 xr4 = *(const ushort4*)(XLR + (long long)d * 512 + 256 + c0);
  float xr0 = bf2f(xr4.x), xr1 = bf2f(xr4.y), xr2 = bf2f(xr4.z), xr3 = bf2f(xr4.w);
  float4 at = *(const float4*)(att + c0);

  float m = -INFINITY, l = 0.f;
  float a0 = 0.f, a1 = 0.f, a2 = 0.f, a3 = 0.f;
  int p = indptr[d], pend = indptr[d + 1];
  ushort4 z4 = make_ushort4(0, 0, 0, 0);
#define LD2(ix) (*(const ushort4*)(XLR + (long long)esrc[ix] * 512 + c0))
  ushort4 qa = (p < pend) ? LD2(p) : z4;
  ushort4 qb = (p + 1 < pend) ? LD2(p + 1) : z4;
  ushort4 ra = (p + 2 < pend) ? LD2(p + 2) : z4;
  ushort4 rb = (p + 3 < pend) ? LD2(p + 3) : z4;
  int i = p;
  for (; i + 1 < pend; i += 2) {
    ushort4 ca = qa, cb = qb;
    qa = ra; qb = rb;
    ra = (i + 4 < pend) ? LD2(i + 4) : z4;
    rb = (i + 5 < pend) ? LD2(i + 5) : z4;
    float xa0 = bf2f(ca.x), xa1 = bf2f(ca.y), xa2 = bf2f(ca.z), xa3 = bf2f(ca.w);
    float xb0 = bf2f(cb.x), xb1 = bf2f(cb.y), xb2 = bf2f(cb.z), xb3 = bf2f(cb.w);
    float ta0 = xa0 + xr0, ta1 = xa1 + xr1, ta2 = xa2 + xr2, ta3 = xa3 + xr3;
    float tb0 = xb0 + xr0, tb1 = xb1 + xr1, tb2 = xb2 + xr2, tb3 = xb3 + xr3;
    ta0 = ta0 > 0.f ? ta0 : NEG * ta0;  ta1 = ta1 > 0.f ? ta1 : NEG * ta1;
    ta2 = ta2 > 0.f ? ta2 : NEG * ta2;  ta3 = ta3 > 0.f ? ta3 : NEG * ta3;
    tb0 = tb0 > 0.f ? tb0 : NEG * tb0;  tb1 = tb1 > 0.f ? tb1 : NEG * tb1;
    tb2 = tb2 > 0.f ? tb2 : NEG * tb2;  tb3 = tb3 > 0.f ? tb3 : NEG * tb3;
    float sa = at.x * ta0 + at.y * ta1 + at.z * ta2 + at.w * ta3;
    float sb = at.x * tb0 + at.y * tb1 + at.z * tb2 + at.w * tb3;
#pragma unroll
    for (int off = 1; off < 64; off <<= 1) {
      sa += __shfl_xor(sa, off);
      sb += __shfl_xor(sb, off);
    }
    float mnew = fmaxf(fmaxf(m, sa), sb);
    float scale = __expf(m - mnew);
    float wa = __expf(sa - mnew);
    float wb = __expf(sb - mnew);
    l = l * scale + wa + wb;
    a0 = a0 * scale + wa * xa0 + wb * xb0;
    a1 = a1 * scale + wa * xa1 + wb * xb1;
    a2 = a2 * scale + wa * xa2 + wb * xb2;
    a3 = a3 * scale + wa * xa3 + wb * xb3;
    m = mnew;
  }
  if (i < pend) {
    float xa0 = bf2f(qa.x), xa1 = bf2f(qa.y), xa2 = bf2f(qa.z), xa3 = bf2f(qa.w);
    float ta0 = xa0 + xr0, ta1 = xa1 + xr1, ta2 = xa2 + xr2, ta3 = xa3 + xr3;
    ta0 = ta0 > 0.f ? ta0 : NEG * ta0;  ta1 = ta1 > 0.f ? ta1 : NEG * ta1;
    ta2 = ta2 > 0.f ? ta2 : NEG * ta2;  ta3 = ta3 > 0.f ? ta3 : NEG * ta3;
    float sa = at.x * ta0 + at.y * ta1 + at.z * ta2 + at.w * ta3;
#pragma unroll
    for (int off = 1; off < 64; off <<= 1) sa += __shfl_xor(sa, off);
    float mnew = fmaxf(m, sa);
    float scale = __expf(m - mnew);
    float wa = __expf(sa - mnew);
    l = l * scale + wa;
    a0 = a0 * scale + wa * xa0;
    a1 = a1 * scale + wa * xa1;
    a2 = a2 * scale + wa * xa2;
    a3 = a3 * scale + wa * xa3;
  }
#undef LD2
  float inv = 1.f / (l + 1e-16f);
  float4 b = *(const float4*)(bias + c0);
  float4 o;
  o.x = fmaxf(a0 * inv + b.x, 0.f);
  o.y = fmaxf(a1 * inv + b.y, 0.f);
  o.z = fmaxf(a2 * inv + b.z, 0.f);
  o.w = fmaxf(a3 * inv + b.w, 0.f);
  *(float4*)(out + (long long)d * C2 + c0) = o;
}

// =============================================================================
extern "C" void kernel_launch(void* const* d_in, const int* in_sizes, int n_in,
                              void* d_out, int out_size, void* d_ws, size_t ws_size,
                              hipStream_t stream) {
  const float* x     = (const float*)d_in[0];
  const int*   ei    = (const int*)d_in[1];
  const float* W1l   = (const float*)d_in[2];
  const float* b1l   = (const float*)d_in[3];
  const float* W1r   = (const float*)d_in[4];
  const float* b1r   = (const float*)d_in[5];
  const float* att1  = (const float*)d_in[6];
  const float* bias1 = (const float*)d_in[7];
  const float* W2l   = (const float*)d_in[8];
  const float* b2l   = (const float*)d_in[9];
  const float* W2r   = (const float*)d_in[10];
  const float* b2r   = (const float*)d_in[11];
  const float* att2  = (const float*)d_in[12];
  const float* bias2 = (const float*)d_in[13];

  const int N  = in_sizes[0] / D_IN;  // 50000
  const int E0 = in_sizes[1] / 2;     // 400000
  const int E  = E0 + N;              // with self-loops
  const int Mp = (N + 255) & ~255;    // 50176 (multiple of 256)
  const int NB = (N + 255) / 256;     // scan blocks (196)

  char* p = (char*)d_ws;
  auto alloc = [&](size_t bytes) -> char* {
    char* r = p;
    p += (bytes + 255) & ~(size_t)255;
    return r;
  };
  u16* X2    = (u16*)alloc((size_t)Mp * D_IN * 2);   // layer-2 GEMM input (bf16)
  u16* XLR1  = (u16*)alloc((size_t)Mp * 2048 * 2);   // [xl|xr] layer 1; later XLR2
  u16* W1t   = (u16*)alloc((size_t)2048 * D_IN * 2);
  u16* W2t   = (u16*)alloc((size_t)512 * C1 * 2);
  float* bc1 = (float*)alloc(2048 * 4);
  float* bc2 = (float*)alloc(512 * 4);
  int* counts = (int*)alloc((size_t)N * 4);
  int* cursor = (int*)alloc((size_t)N * 4);
  int* indptr = (int*)alloc((size_t)(N + 1) * 4);
  int* esrc   = (int*)alloc((size_t)E * 4);
  int* bsum   = (int*)alloc((size_t)NB * 4);
  int* boff   = (int*)alloc((size_t)NB * 4);
  u16* XLR2 = XLR1;   // alias: XLR1 dead after fused_edge1

  size_t need = (size_t)(p - (char*)d_ws);
  if (ws_size < need) {
    hipMemsetAsync(d_out, 0xFF, 4, stream);  // NaN sentinel
    return;
  }

  hipMemsetAsync(counts, 0, (size_t)N * 4, stream);
  hipMemsetAsync(cursor, 0, (size_t)N * 4, stream);

  // ---- transposes / bias concat (no cast_x: GEMM1 reads f32 x directly) ----
  dim3 tb(32, 8);
  transpose_cast_k<<<dim3(D_IN / 32, C1 / 32), tb, 0, stream>>>(W1l, W1t, D_IN, C1);
  transpose_cast_k<<<dim3(D_IN / 32, C1 / 32), tb, 0, stream>>>(W1r, W1t + (size_t)1024 * D_IN, D_IN, C1);
  transpose_cast_k<<<dim3(C1 / 32, C2 / 32), tb, 0, stream>>>(W2l, W2t, C1, C2);
  transpose_cast_k<<<dim3(C1 / 32, C2 / 32), tb, 0, stream>>>(W2r, W2t + (size_t)256 * C1, C1, C2);
  concat_bias_k<<<8, 256, 0, stream>>>(b1l, b1r, bc1, 1024, 1024);
  concat_bias_k<<<2, 256, 0, stream>>>(b2l, b2r, bc2, 256, 256);

  // ---- CSR by dst (shared by both layers) ----
  count_k<<<1024, 256, 0, stream>>>(ei, counts, E0, E);
  blocksum_k<<<NB, 256, 0, stream>>>(counts, bsum, N);
  scanb_k<<<1, 256, 0, stream>>>(bsum, boff, NB, indptr, N, E);
  scanf_k<<<NB, 256, 0, stream>>>(counts, boff, indptr, N);
  scatter_k<<<1024, 256, 0, stream>>>(ei, indptr, cursor, esrc, E0, E);

  // ---- layer 1 (A = raw f32 x, clamped rows; pad rows of XLR1 are garbage
  //      but never read: edge kernels index only src/dst < N) ----
  gemm8_k<2048, true><<<dim3(Mp / 256, 2048 / 256), 512, 0, stream>>>(
      x, W1t, bc1, XLR1, D_IN, N);
  fused_edge1_k<<<Mp, 256, 0, stream>>>(XLR1, indptr, esrc, att1, bias1, X2, N);

  // ---- layer 2 (A = bf16 X2; pad rows zeroed by fused_edge1) ----
  gemm8_k<512, false><<<dim3(Mp / 256, 512 / 256), 512, 0, stream>>>(
      X2, W2t, bc2, XLR2, C1, N);
  fused_edge2_k<<<(N + 3) / 4, 256, 0, stream>>>(XLR2, indptr, esrc, att2, bias2,
                                                 (float*)d_out, N);
}

// Round 9
// 686.080 us; speedup vs baseline: 1.1512x; 1.1512x over previous
//
#include <hip/hip_runtime.h>
#include <stdint.h>

#define D_IN 1024
#define C1   1024   // H1*HID
#define C2   256    // H2*HID
#define NEG  0.2f

typedef unsigned int u32;
typedef uint16_t u16;
typedef __attribute__((ext_vector_type(8))) short bf16x8;
typedef __attribute__((ext_vector_type(4))) float f32x4;

__device__ __forceinline__ float bf2f(u32 lo16) { return __uint_as_float(lo16 << 16); }
__device__ __forceinline__ u16 f2bf(float f) {
  u32 u = __float_as_uint(f);
  u += 0x7fffu + ((u >> 16) & 1u);   // RNE
  return (u16)(u >> 16);
}

__device__ __forceinline__ void gload16(const u16* g, u16* l) {
  __builtin_amdgcn_global_load_lds(
      (const __attribute__((address_space(1))) unsigned int*)g,
      (__attribute__((address_space(3))) unsigned int*)l,
      16, 0, 0);
}

// ---------------- cast x (f32) -> padded bf16 A [Mp][1024], zero pad rows ----
__global__ void cast_x_k(const float* __restrict__ x, u16* __restrict__ A,
                         int nrows, int Mp) {
  long long idx = (long long)blockIdx.x * blockDim.x + threadIdx.x;
  long long total = (long long)Mp * (D_IN / 8);
  if (idx >= total) return;
  long long base = idx * 8;
  int row = (int)(base >> 10);  // D_IN==1024
  u32 o0 = 0, o1 = 0, o2 = 0, o3 = 0;
  if (row < nrows) {
    const float4* px = (const float4*)(x + base);
    float4 v0 = px[0], v1 = px[1];
    o0 = (u32)f2bf(v0.x) | ((u32)f2bf(v0.y) << 16);
    o1 = (u32)f2bf(v0.z) | ((u32)f2bf(v0.w) << 16);
    o2 = (u32)f2bf(v1.x) | ((u32)f2bf(v1.y) << 16);
    o3 = (u32)f2bf(v1.z) | ((u32)f2bf(v1.w) << 16);
  }
  *(uint4*)(A + base) = make_uint4(o0, o1, o2, o3);
}

// ---- fused prep: 4 transpose+casts in one dispatch (blockIdx.z selects) ----
// z=0: W1l [1024x1024] -> W1t;        z=1: W1r -> W1t + 1024*1024
// z=2: W2l [1024x256]  -> W2t;        z=3: W2r -> W2t + 256*1024
__global__ void prep_w_k(const float* __restrict__ W1l, const float* __restrict__ W1r,
                         const float* __restrict__ W2l, const float* __restrict__ W2r,
                         u16* __restrict__ W1t, u16* __restrict__ W2t) {
  __shared__ float sh[32][33];
  int z = blockIdx.z;
  const float* W;
  u16* Wt;
  int K = 1024, Nc;
  if (z == 0)      { W = W1l; Wt = W1t;                         Nc = 1024; }
  else if (z == 1) { W = W1r; Wt = W1t + (size_t)1024 * 1024;   Nc = 1024; }
  else if (z == 2) { W = W2l; Wt = W2t;                         Nc = 256;  }
  else             { W = W2r; Wt = W2t + (size_t)256 * 1024;    Nc = 256;  }
  int n0 = blockIdx.y * 32;
  if (n0 >= Nc) return;
  int k0 = blockIdx.x * 32;
  int tx = threadIdx.x, ty = threadIdx.y;  // block (32,8)
#pragma unroll
  for (int i = 0; i < 32; i += 8)
    sh[ty + i][tx] = W[(long long)(k0 + ty + i) * Nc + (n0 + tx)];
  __syncthreads();
#pragma unroll
  for (int i = 0; i < 32; i += 8)
    Wt[(long long)(n0 + ty + i) * K + (k0 + tx)] = f2bf(sh[tx][ty + i]);
}

// ---- fused bias concat: bc1 = [b1l|b1r] (2048), bc2 = [b2l|b2r] (512) ------
__global__ void prep_b_k(const float* __restrict__ b1l, const float* __restrict__ b1r,
                         const float* __restrict__ b2l, const float* __restrict__ b2r,
                         float* __restrict__ bc1, float* __restrict__ bc2) {
  int i = blockIdx.x * 256 + threadIdx.x;
  if (i < 1024) bc1[i] = b1l[i];
  else if (i < 2048) bc1[i] = b1r[i - 1024];
  else if (i < 2304) bc2[i - 2048] = b2l[i - 2048];
  else if (i < 2560) bc2[i - 2048] = b2r[i - 2304];
}

// ============ 256x256 BK=64 8-wave phase-interleaved MFMA GEMM ===============
// r4 schedule (best measured: 288us over 5 variants — do not retune).
// 512 thr = 8 waves (2M x 4N), per-wave 128x64 (acc[8][4]).  LDS 128 KiB dbuf.
// Stage slots: ph1:A1(t+1)  ph2:B0(t+1)  ph3:B1(t+1)  ph4:A0(t+2);
// ONE counted s_waitcnt vmcnt(2) per K-tile (A0(t+2) in flight), drain 0 at
// tail.  LDS chunk-XOR swizzle via pre-swizzled global source (rule #21).
template <int TN>
__global__ __launch_bounds__(512, 2) void gemm8_k(
    const u16* __restrict__ A, const u16* __restrict__ Bt,
    const float* __restrict__ bias, u16* __restrict__ C, int K) {
  __shared__ u16 As[2][2][8192];
  __shared__ u16 Bs[2][2][8192];
  const int nx = gridDim.x, ny = gridDim.y;
  const int nwg = nx * ny;
  int id = blockIdx.y * nx + blockIdx.x;
  int q = nwg >> 3, r = nwg & 7;
  int xcd = id & 7, loc = id >> 3;
  int sid = (xcd < r ? xcd * (q + 1) : r * (q + 1) + (xcd - r) * q) + loc;
  const int m0 = (sid / ny) * 256;   // n varies fastest within an XCD
  const int n0 = (sid % ny) * 256;

  const int tid = threadIdx.x;
  const int lane = tid & 63;
  const int wave = tid >> 6;
  const int wm = wave >> 2;          // 0..1  (A half)
  const int wn = wave & 3;           // 0..3
  const int bh = wn >> 1;            // B half this wave reads
  const int bql = (wn & 1) * 2048;   // B quarter offset within half (u16)

  const int srow = tid >> 2;         // staging row 0..127
  const int kq   = tid & 3;          // physical k-chunk
  const int ksw  = (kq ^ ((srow >> 1) & 3)) * 8;  // swizzled src col (u16)

  const int nt = K / 64;

  const u16* gA[2] = { A + (long long)(m0 + srow) * K + ksw,
                       A + (long long)(m0 + 128 + srow) * K + ksw };
  const u16* gB[2] = { Bt + (long long)(n0 + srow) * K + ksw,
                       Bt + (long long)(n0 + 128 + srow) * K + ksw };

  auto stageA = [&](int kt, int h) {
    int db = kt & 1;
    gload16(gA[h] + kt * 64,      &As[db][h][tid * 8]);
    gload16(gA[h] + kt * 64 + 32, &As[db][h][4096 + tid * 8]);
  };
  auto stageB = [&](int kt, int h) {
    int db = kt & 1;
    gload16(gB[h] + kt * 64,      &Bs[db][h][tid * 8]);
    gload16(gB[h] + kt * 64 + 32, &Bs[db][h][4096 + tid * 8]);
  };

  // fragment read base: frow*32 + physchunk*8 (u16), physchunk = lq ^ s(frow)
  const int rbase = (lane & 15) * 32 + (((lane >> 4) ^ ((lane >> 1) & 3)) << 3);

  f32x4 acc[8][4] = {};
  bf16x8 av[4][2], bv[4][2];

  // ---- prologue: tile0 fully + A0(tile1); counted wait ----
  stageA(0, 0); stageA(0, 1); stageB(0, 0); stageB(0, 1);
  if (nt > 1) {
    stageA(1, 0);
    asm volatile("s_waitcnt vmcnt(2)" ::: "memory");
  } else {
    asm volatile("s_waitcnt vmcnt(0)" ::: "memory");
  }
  __builtin_amdgcn_s_barrier();

  for (int t = 0; t < nt; ++t) {
    const int cur = t & 1;
    const u16* Al = &As[cur][wm][0];
    const u16* Bl = &Bs[cur][bh][0];

    // ---- phase 1: Q1 (m 0..3, n 0..1); stage A1(t+1) ----
#pragma unroll
    for (int i = 0; i < 4; ++i) {
      av[i][0] = *(const bf16x8*)(Al + i * 512 + rbase);
      av[i][1] = *(const bf16x8*)(Al + 4096 + i * 512 + rbase);
    }
#pragma unroll
    for (int j = 0; j < 2; ++j) {
      bv[j][0] = *(const bf16x8*)(Bl + bql + j * 512 + rbase);
      bv[j][1] = *(const bf16x8*)(Bl + 4096 + bql + j * 512 + rbase);
    }
    if (t + 1 < nt) stageA(t + 1, 1);
    __builtin_amdgcn_s_barrier();
    __builtin_amdgcn_s_setprio(1);
#pragma unroll
    for (int i = 0; i < 4; ++i)
#pragma unroll
      for (int j = 0; j < 2; ++j) {
        acc[i][j] = __builtin_amdgcn_mfma_f32_16x16x32_bf16(av[i][0], bv[j][0], acc[i][j], 0, 0, 0);
        acc[i][j] = __builtin_amdgcn_mfma_f32_16x16x32_bf16(av[i][1], bv[j][1], acc[i][j], 0, 0, 0);
      }
    __builtin_amdgcn_s_setprio(0);
    __builtin_amdgcn_s_barrier();

    // ---- phase 2: Q2 (m 0..3, n 2..3); stage B0(t+1) ----
#pragma unroll
    for (int j = 2; j < 4; ++j) {
      bv[j][0] = *(const bf16x8*)(Bl + bql + j * 512 + rbase);
      bv[j][1] = *(const bf16x8*)(Bl + 4096 + bql + j * 512 + rbase);
    }
    if (t + 1 < nt) stageB(t + 1, 0);
    __builtin_amdgcn_s_barrier();
    __builtin_amdgcn_s_setprio(1);
#pragma unroll
    for (int i = 0; i < 4; ++i)
#pragma unroll
      for (int j = 2; j < 4; ++j) {
        acc[i][j] = __builtin_amdgcn_mfma_f32_16x16x32_bf16(av[i][0], bv[j][0], acc[i][j], 0, 0, 0);
        acc[i][j] = __builtin_amdgcn_mfma_f32_16x16x32_bf16(av[i][1], bv[j][1], acc[i][j], 0, 0, 0);
      }
    __builtin_amdgcn_s_setprio(0);
    __builtin_amdgcn_s_barrier();

    // ---- phase 3: Q3 (m 4..7, n 2..3); stage B1(t+1) ----
#pragma unroll
    for (int i = 0; i < 4; ++i) {
      av[i][0] = *(const bf16x8*)(Al + (4 + i) * 512 + rbase);
      av[i][1] = *(const bf16x8*)(Al + 4096 + (4 + i) * 512 + rbase);
    }
    if (t + 1 < nt) stageB(t + 1, 1);
    __builtin_amdgcn_s_barrier();
    __builtin_amdgcn_s_setprio(1);
#pragma unroll
    for (int i = 0; i < 4; ++i)
#pragma unroll
      for (int j = 2; j < 4; ++j) {
        acc[4 + i][j] = __builtin_amdgcn_mfma_f32_16x16x32_bf16(av[i][0], bv[j][0], acc[4 + i][j], 0, 0, 0);
        acc[4 + i][j] = __builtin_amdgcn_mfma_f32_16x16x32_bf16(av[i][1], bv[j][1], acc[4 + i][j], 0, 0, 0);
      }
    __builtin_amdgcn_s_setprio(0);
    __builtin_amdgcn_s_barrier();

    // ---- phase 4: Q4 (m 4..7, n 0..1); stage A0(t+2) ----
    if (t + 2 < nt) stageA(t + 2, 0);
    __builtin_amdgcn_s_barrier();
    __builtin_amdgcn_s_setprio(1);
#pragma unroll
    for (int i = 0; i < 4; ++i)
#pragma unroll
      for (int j = 0; j < 2; ++j) {
        acc[4 + i][j] = __builtin_amdgcn_mfma_f32_16x16x32_bf16(av[i][0], bv[j][0], acc[4 + i][j], 0, 0, 0);
        acc[4 + i][j] = __builtin_amdgcn_mfma_f32_16x16x32_bf16(av[i][1], bv[j][1], acc[4 + i][j], 0, 0, 0);
      }
    __builtin_amdgcn_s_setprio(0);
    if (t + 2 < nt) {
      asm volatile("s_waitcnt vmcnt(2)" ::: "memory");
    } else if (t + 1 < nt) {
      asm volatile("s_waitcnt vmcnt(0)" ::: "memory");
    }
    __builtin_amdgcn_s_barrier();
  }

  // ---- epilogue: D mapping col=lane&15, row=(lane>>4)*4+j ----
#pragma unroll
  for (int mf = 0; mf < 8; ++mf) {
    int r0 = m0 + wm * 128 + mf * 16 + ((lane >> 4) << 2);
#pragma unroll
    for (int nf = 0; nf < 4; ++nf) {
      int c = n0 + wn * 64 + nf * 16 + (lane & 15);
      float b = bias[c];
#pragma unroll
      for (int j = 0; j < 4; ++j)
        C[(long long)(r0 + j) * TN + c] = f2bf(acc[mf][nf][j] + b);
    }
  }
}

// ---------------- CSR build (by dst) ----------------------------------------
__global__ void count_k(const int* __restrict__ ei, int* __restrict__ counts,
                        int E0, int E) {
  for (int e = blockIdx.x * blockDim.x + threadIdx.x; e < E;
       e += gridDim.x * blockDim.x) {
    int dst = (e < E0) ? ei[E0 + e] : e - E0;
    atomicAdd(&counts[dst], 1);
  }
}

__global__ void blocksum_k(const int* __restrict__ counts, int* __restrict__ bsum, int n) {
  int i = blockIdx.x * 256 + threadIdx.x;
  int v = (i < n) ? counts[i] : 0;
#pragma unroll
  for (int off = 1; off < 64; off <<= 1) v += __shfl_xor(v, off);
  __shared__ int sh[4];
  if ((threadIdx.x & 63) == 0) sh[threadIdx.x >> 6] = v;
  __syncthreads();
  if (threadIdx.x == 0) bsum[blockIdx.x] = sh[0] + sh[1] + sh[2] + sh[3];
}

__global__ void scanb_k(const int* __restrict__ bsum, int* __restrict__ boff,
                        int nb, int* __restrict__ indptr, int n, int E) {
  __shared__ int sh[256];
  int i = threadIdx.x;
  int v = (i < nb) ? bsum[i] : 0;
  sh[i] = v;
  __syncthreads();
  int sum = v;
  for (int off = 1; off < 256; off <<= 1) {
    int t = (i >= off) ? sh[i - off] : 0;
    __syncthreads();
    sum += t;
    sh[i] = sum;
    __syncthreads();
  }
  if (i < nb) boff[i] = sum - v;  // exclusive
  if (i == 0) indptr[n] = E;
}

__global__ void scanf_k(const int* __restrict__ counts, const int* __restrict__ boff,
                        int* __restrict__ indptr, int n) {
  __shared__ int sh[256];
  int b = blockIdx.x;
  int i = b * 256 + threadIdx.x;
  int v = (i < n) ? counts[i] : 0;
  sh[threadIdx.x] = v;
  __syncthreads();
  int sum = v;
  for (int off = 1; off < 256; off <<= 1) {
    int t = (threadIdx.x >= off) ? sh[threadIdx.x - off] : 0;
    __syncthreads();
    sum += t;
    sh[threadIdx.x] = sum;
    __syncthreads();
  }
  if (i < n) indptr[i] = boff[b] + sum - v;
}

// store SRC id (not edge id) in CSR order
__global__ void scatter_k(const int* __restrict__ ei, const int* __restrict__ indptr,
                          int* __restrict__ cursor, int* __restrict__ esrc,
                          int E0, int E) {
  for (int e = blockIdx.x * blockDim.x + threadIdx.x; e < E;
       e += gridDim.x * blockDim.x) {
    int dst, src;
    if (e < E0) { src = ei[e]; dst = ei[E0 + e]; } else { src = dst = e - E0; }
    int pos = atomicAdd(&cursor[dst], 1);
    esrc[indptr[dst] + pos] = src;
  }
}

// ---------------- fused edge layer 1 (H=4): alpha+softmax+agg, online --------
__global__ __launch_bounds__(256) void fused_edge1_k(
    const u16* __restrict__ XLR, const int* __restrict__ indptr,
    const int* __restrict__ esrc, const float* __restrict__ att,
    const float* __restrict__ bias, u16* __restrict__ X2, int N) {
  int d = blockIdx.x;
  int tid = threadIdx.x;
  int c0 = tid * 4;  // channel in [0,1024); head = tid>>6
  if (d >= N) {
    *(ushort4*)(X2 + (long long)d * C1 + c0) = make_ushort4(0, 0, 0, 0);
    return;
  }
  ushort4 xr4 = *(const ushort4*)(XLR + (long long)d * 2048 + 1024 + c0);
  float xr0 = bf2f(xr4.x), xr1 = bf2f(xr4.y), xr2 = bf2f(xr4.z), xr3 = bf2f(xr4.w);
  float4 at = *(const float4*)(att + c0);

  float m = -INFINITY, l = 0.f;
  float a0 = 0.f, a1 = 0.f, a2 = 0.f, a3 = 0.f;
  int p = indptr[d], pend = indptr[d + 1];
  ushort4 z4 = make_ushort4(0, 0, 0, 0);
#define LD1(ix) (*(const ushort4*)(XLR + (long long)esrc[ix] * 2048 + c0))
  ushort4 qa = (p < pend) ? LD1(p) : z4;
  ushort4 qb = (p + 1 < pend) ? LD1(p + 1) : z4;
  ushort4 ra = (p + 2 < pend) ? LD1(p + 2) : z4;
  ushort4 rb = (p + 3 < pend) ? LD1(p + 3) : z4;
  int i = p;
  for (; i + 1 < pend; i += 2) {
    ushort4 ca = qa, cb = qb;
    qa = ra; qb = rb;
    ra = (i + 4 < pend) ? LD1(i + 4) : z4;
    rb = (i + 5 < pend) ? LD1(i + 5) : z4;
    float xa0 = bf2f(ca.x), xa1 = bf2f(ca.y), xa2 = bf2f(ca.z), xa3 = bf2f(ca.w);
    float xb0 = bf2f(cb.x), xb1 = bf2f(cb.y), xb2 = bf2f(cb.z), xb3 = bf2f(cb.w);
    float ta0 = xa0 + xr0, ta1 = xa1 + xr1, ta2 = xa2 + xr2, ta3 = xa3 + xr3;
    float tb0 = xb0 + xr0, tb1 = xb1 + xr1, tb2 = xb2 + xr2, tb3 = xb3 + xr3;
    ta0 = ta0 > 0.f ? ta0 : NEG * ta0;  ta1 = ta1 > 0.f ? ta1 : NEG * ta1;
    ta2 = ta2 > 0.f ? ta2 : NEG * ta2;  ta3 = ta3 > 0.f ? ta3 : NEG * ta3;
    tb0 = tb0 > 0.f ? tb0 : NEG * tb0;  tb1 = tb1 > 0.f ? tb1 : NEG * tb1;
    tb2 = tb2 > 0.f ? tb2 : NEG * tb2;  tb3 = tb3 > 0.f ? tb3 : NEG * tb3;
    float sa = at.x * ta0 + at.y * ta1 + at.z * ta2 + at.w * ta3;
    float sb = at.x * tb0 + at.y * tb1 + at.z * tb2 + at.w * tb3;
#pragma unroll
    for (int off = 1; off < 64; off <<= 1) {
      sa += __shfl_xor(sa, off);
      sb += __shfl_xor(sb, off);
    }
    float mnew = fmaxf(fmaxf(m, sa), sb);
    float scale = __expf(m - mnew);
    float wa = __expf(sa - mnew);
    float wb = __expf(sb - mnew);
    l = l * scale + wa + wb;
    a0 = a0 * scale + wa * xa0 + wb * xb0;
    a1 = a1 * scale + wa * xa1 + wb * xb1;
    a2 = a2 * scale + wa * xa2 + wb * xb2;
    a3 = a3 * scale + wa * xa3 + wb * xb3;
    m = mnew;
  }
  if (i < pend) {  // tail single edge (data in qa)
    float xa0 = bf2f(qa.x), xa1 = bf2f(qa.y), xa2 = bf2f(qa.z), xa3 = bf2f(qa.w);
    float ta0 = xa0 + xr0, ta1 = xa1 + xr1, ta2 = xa2 + xr2, ta3 = xa3 + xr3;
    ta0 = ta0 > 0.f ? ta0 : NEG * ta0;  ta1 = ta1 > 0.f ? ta1 : NEG * ta1;
    ta2 = ta2 > 0.f ? ta2 : NEG * ta2;  ta3 = ta3 > 0.f ? ta3 : NEG * ta3;
    float sa = at.x * ta0 + at.y * ta1 + at.z * ta2 + at.w * ta3;
#pragma unroll
    for (int off = 1; off < 64; off <<= 1) sa += __shfl_xor(sa, off);
    float mnew = fmaxf(m, sa);
    float scale = __expf(m - mnew);
    float wa = __expf(sa - mnew);
    l = l * scale + wa;
    a0 = a0 * scale + wa * xa0;
    a1 = a1 * scale + wa * xa1;
    a2 = a2 * scale + wa * xa2;
    a3 = a3 * scale + wa * xa3;
  }
#undef LD1
  float inv = 1.f / (l + 1e-16f);
  float4 b = *(const float4*)(bias + c0);
  ushort4 o;
  o.x = f2bf(fmaxf(a0 * inv + b.x, 0.f));
  o.y = f2bf(fmaxf(a1 * inv + b.y, 0.f));
  o.z = f2bf(fmaxf(a2 * inv + b.z, 0.f));
  o.w = f2bf(fmaxf(a3 * inv + b.w, 0.f));
  *(ushort4*)(X2 + (long long)d * C1 + c0) = o;
}

// ---------------- fused edge layer 2 (H=1): one wave per dst, f32 out --------
__global__ __launch_bounds__(256) void fused_edge2_k(
    const u16* __restrict__ XLR, const int* __restrict__ indptr,
    const int* __restrict__ esrc, const float* __restrict__ att,
    const float* __restrict__ bias, float* __restrict__ out, int N) {
  int d = blockIdx.x * 4 + (threadIdx.x >> 6);
  if (d >= N) return;
  int lane = threadIdx.x & 63;
  int c0 = lane * 4;
  ushort4 xr4 = *(const ushort4*)(XLR + (long long)d * 512 + 256 + c0);
  float xr0 = bf2f(xr4.x), xr1 = bf2f(xr4.y), xr2 = bf2f(xr4.z), xr3 = bf2f(xr4.w);
  float4 at = *(const float4*)(att + c0);

  float m = -INFINITY, l = 0.f;
  float a0 = 0.f, a1 = 0.f, a2 = 0.f, a3 = 0.f;
  int p = indptr[d], pend = indptr[d + 1];
  ushort4 z4 = make_ushort4(0, 0, 0, 0);
#define LD2(ix) (*(const ushort4*)(XLR + (long long)esrc[ix] * 512 + c0))
  ushort4 qa = (p < pend) ? LD2(p) : z4;
  ushort4 qb = (p + 1 < pend) ? LD2(p + 1) : z4;
  ushort4 ra = (p + 2 < pend) ? LD2(p + 2) : z4;
  ushort4 rb = (p + 3 < pend) ? LD2(p + 3) : z4;
  int i = p;
  for (; i + 1 < pend; i += 2) {
    ushort4 ca = qa, cb = qb;
    qa = ra; qb = rb;
    ra = (i + 4 < pend) ? LD2(i + 4) : z4;
    rb = (i + 5 < pend) ? LD2(i + 5) : z4;
    float xa0 = bf2f(ca.x), xa1 = bf2f(ca.y), xa2 = bf2f(ca.z), xa3 = bf2f(ca.w);
    float xb0 = bf2f(cb.x), xb1 = bf2f(cb.y), xb2 = bf2f(cb.z), xb3 = bf2f(cb.w);
    float ta0 = xa0 + xr0, ta1 = xa1 + xr1, ta2 = xa2 + xr2, ta3 = xa3 + xr3;
    float tb0 = xb0 + xr0, tb1 = xb1 + xr1, tb2 = xb2 + xr2, tb3 = xb3 + xr3;
    ta0 = ta0 > 0.f ? ta0 : NEG * ta0;  ta1 = ta1 > 0.f ? ta1 : NEG * ta1;
    ta2 = ta2 > 0.f ? ta2 : NEG * ta2;  ta3 = ta3 > 0.f ? ta3 : NEG * ta3;
    tb0 = tb0 > 0.f ? tb0 : NEG * tb0;  tb1 = tb1 > 0.f ? tb1 : NEG * tb1;
    tb2 = tb2 > 0.f ? tb2 : NEG * tb2;  tb3 = tb3 > 0.f ? tb3 : NEG * tb3;
    float sa = at.x * ta0 + at.y * ta1 + at.z * ta2 + at.w * ta3;
    float sb = at.x * tb0 + at.y * tb1 + at.z * tb2 + at.w * tb3;
#pragma unroll
    for (int off = 1; off < 64; off <<= 1) {
      sa += __shfl_xor(sa, off);
      sb += __shfl_xor(sb, off);
    }
    float mnew = fmaxf(fmaxf(m, sa), sb);
    float scale = __expf(m - mnew);
    float wa = __expf(sa - mnew);
    float wb = __expf(sb - mnew);
    l = l * scale + wa + wb;
    a0 = a0 * scale + wa * xa0 + wb * xb0;
    a1 = a1 * scale + wa * xa1 + wb * xb1;
    a2 = a2 * scale + wa * xa2 + wb * xb2;
    a3 = a3 * scale + wa * xa3 + wb * xb3;
    m = mnew;
  }
  if (i < pend) {
    float xa0 = bf2f(qa.x), xa1 = bf2f(qa.y), xa2 = bf2f(qa.z), xa3 = bf2f(qa.w);
    float ta0 = xa0 + xr0, ta1 = xa1 + xr1, ta2 = xa2 + xr2, ta3 = xa3 + xr3;
    ta0 = ta0 > 0.f ? ta0 : NEG * ta0;  ta1 = ta1 > 0.f ? ta1 : NEG * ta1;
    ta2 = ta2 > 0.f ? ta2 : NEG * ta2;  ta3 = ta3 > 0.f ? ta3 : NEG * ta3;
    float sa = at.x * ta0 + at.y * ta1 + at.z * ta2 + at.w * ta3;
#pragma unroll
    for (int off = 1; off < 64; off <<= 1) sa += __shfl_xor(sa, off);
    float mnew = fmaxf(m, sa);
    float scale = __expf(m - mnew);
    float wa = __expf(sa - mnew);
    l = l * scale + wa;
    a0 = a0 * scale + wa * xa0;
    a1 = a1 * scale + wa * xa1;
    a2 = a2 * scale + wa * xa2;
    a3 = a3 * scale + wa * xa3;
  }
#undef LD2
  float inv = 1.f / (l + 1e-16f);
  float4 b = *(const float4*)(bias + c0);
  float4 o;
  o.x = fmaxf(a0 * inv + b.x, 0.f);
  o.y = fmaxf(a1 * inv + b.y, 0.f);
  o.z = fmaxf(a2 * inv + b.z, 0.f);
  o.w = fmaxf(a3 * inv + b.w, 0.f);
  *(float4*)(out + (long long)d * C2 + c0) = o;
}

// =============================================================================
extern "C" void kernel_launch(void* const* d_in, const int* in_sizes, int n_in,
                              void* d_out, int out_size, void* d_ws, size_t ws_size,
                              hipStream_t stream) {
  const float* x     = (const float*)d_in[0];
  const int*   ei    = (const int*)d_in[1];
  const float* W1l   = (const float*)d_in[2];
  const float* b1l   = (const float*)d_in[3];
  const float* W1r   = (const float*)d_in[4];
  const float* b1r   = (const float*)d_in[5];
  const float* att1  = (const float*)d_in[6];
  const float* bias1 = (const float*)d_in[7];
  const float* W2l   = (const float*)d_in[8];
  const float* b2l   = (const float*)d_in[9];
  const float* W2r   = (const float*)d_in[10];
  const float* b2r   = (const float*)d_in[11];
  const float* att2  = (const float*)d_in[12];
  const float* bias2 = (const float*)d_in[13];

  const int N  = in_sizes[0] / D_IN;  // 50000
  const int E0 = in_sizes[1] / 2;     // 400000
  const int E  = E0 + N;              // with self-loops
  const int Mp = (N + 255) & ~255;    // 50176 (multiple of 256)
  const int NB = (N + 255) / 256;     // scan blocks (196)

  char* p = (char*)d_ws;
  auto alloc = [&](size_t bytes) -> char* {
    char* r = p;
    p += (bytes + 255) & ~(size_t)255;
    return r;
  };
  u16* A_bf  = (u16*)alloc((size_t)Mp * D_IN * 2);   // x bf16; later X2 (layer-2 A)
  u16* XLR1  = (u16*)alloc((size_t)Mp * 2048 * 2);   // [xl|xr] layer 1; later XLR2
  u16* W1t   = (u16*)alloc((size_t)2048 * D_IN * 2);
  u16* W2t   = (u16*)alloc((size_t)512 * C1 * 2);
  float* bc1 = (float*)alloc(2048 * 4);
  float* bc2 = (float*)alloc(512 * 4);
  int* counts = (int*)alloc((size_t)N * 4);          // counts+cursor adjacent:
  int* cursor = (int*)alloc((size_t)N * 4);          //  single memset covers both
  int* indptr = (int*)alloc((size_t)(N + 1) * 4);
  int* esrc   = (int*)alloc((size_t)E * 4);
  int* bsum   = (int*)alloc((size_t)NB * 4);
  int* boff   = (int*)alloc((size_t)NB * 4);
  u16* X2   = A_bf;   // alias: A_bf dead after GEMM1
  u16* XLR2 = XLR1;   // alias: XLR1 dead after fused_edge1

  size_t need = (size_t)(p - (char*)d_ws);
  if (ws_size < need) {
    hipMemsetAsync(d_out, 0xFF, 4, stream);  // NaN sentinel
    return;
  }

  // one memset over counts..cursor (contiguous in the arena)
  hipMemsetAsync(counts, 0, (size_t)((char*)cursor - (char*)counts) + (size_t)N * 4,
                 stream);

  // ---- prep: cast x, all W transposes in one dispatch, bias concats ----
  {
    long long tot = (long long)Mp * (D_IN / 8);
    cast_x_k<<<(int)((tot + 255) / 256), 256, 0, stream>>>(x, A_bf, N, Mp);
  }
  prep_w_k<<<dim3(32, 32, 4), dim3(32, 8), 0, stream>>>(W1l, W1r, W2l, W2r, W1t, W2t);
  prep_b_k<<<10, 256, 0, stream>>>(b1l, b1r, b2l, b2r, bc1, bc2);

  // ---- CSR by dst (shared by both layers) ----
  count_k<<<1024, 256, 0, stream>>>(ei, counts, E0, E);
  blocksum_k<<<NB, 256, 0, stream>>>(counts, bsum, N);
  scanb_k<<<1, 256, 0, stream>>>(bsum, boff, NB, indptr, N, E);
  scanf_k<<<NB, 256, 0, stream>>>(counts, boff, indptr, N);
  scatter_k<<<1024, 256, 0, stream>>>(ei, indptr, cursor, esrc, E0, E);

  // ---- layer 1 ----
  gemm8_k<2048><<<dim3(Mp / 256, 2048 / 256), 512, 0, stream>>>(A_bf, W1t, bc1, XLR1, D_IN);
  fused_edge1_k<<<Mp, 256, 0, stream>>>(XLR1, indptr, esrc, att1, bias1, X2, N);

  // ---- layer 2 ----
  gemm8_k<512><<<dim3(Mp / 256, 512 / 256), 512, 0, stream>>>(X2, W2t, bc2, XLR2, C1);
  fused_edge2_k<<<(N + 3) / 4, 256, 0, stream>>>(XLR2, indptr, esrc, att2, bias2,
                                                 (float*)d_out, N);
}

// Round 10
// 659.746 us; speedup vs baseline: 1.1971x; 1.0399x over previous
//
#include <hip/hip_runtime.h>
#include <stdint.h>

#define D_IN 1024
#define C1   1024   // H1*HID
#define C2   256    // H2*HID
#define NEG  0.2f

typedef unsigned int u32;
typedef uint16_t u16;
typedef __attribute__((ext_vector_type(8))) short bf16x8;
typedef __attribute__((ext_vector_type(4))) float f32x4;

__device__ __forceinline__ float bf2f(u32 lo16) { return __uint_as_float(lo16 << 16); }
__device__ __forceinline__ u16 f2bf(float f) {
  u32 u = __float_as_uint(f);
  u += 0x7fffu + ((u >> 16) & 1u);   // RNE
  return (u16)(u >> 16);
}

__device__ __forceinline__ void gload16(const u16* g, u16* l) {
  __builtin_amdgcn_global_load_lds(
      (const __attribute__((address_space(1))) unsigned int*)g,
      (__attribute__((address_space(3))) unsigned int*)l,
      16, 0, 0);
}

// ---- fused cast_x + edge count (one dispatch; disjoint block ranges) --------
// blocks [0, CB): cast x f32 -> padded bf16 A; blocks [CB, CB+1024): count.
__global__ void cast_count_k(const float* __restrict__ x, u16* __restrict__ A,
                             int nrows, int Mp, int CB,
                             const int* __restrict__ ei, int* __restrict__ counts,
                             int E0, int E) {
  if ((int)blockIdx.x < CB) {
    long long idx = (long long)blockIdx.x * blockDim.x + threadIdx.x;
    long long total = (long long)Mp * (D_IN / 8);
    if (idx >= total) return;
    long long base = idx * 8;
    int row = (int)(base >> 10);  // D_IN==1024
    u32 o0 = 0, o1 = 0, o2 = 0, o3 = 0;
    if (row < nrows) {
      const float4* px = (const float4*)(x + base);
      float4 v0 = px[0], v1 = px[1];
      o0 = (u32)f2bf(v0.x) | ((u32)f2bf(v0.y) << 16);
      o1 = (u32)f2bf(v0.z) | ((u32)f2bf(v0.w) << 16);
      o2 = (u32)f2bf(v1.x) | ((u32)f2bf(v1.y) << 16);
      o3 = (u32)f2bf(v1.z) | ((u32)f2bf(v1.w) << 16);
    }
    *(uint4*)(A + base) = make_uint4(o0, o1, o2, o3);
  } else {
    int nb = gridDim.x - CB;
    for (int e = ((int)blockIdx.x - CB) * blockDim.x + threadIdx.x; e < E;
         e += nb * blockDim.x) {
      int dst = (e < E0) ? ei[E0 + e] : e - E0;
      atomicAdd(&counts[dst], 1);
    }
  }
}

// ---- fused prep: 4 transpose+casts in one dispatch (blockIdx.z selects) ----
__global__ void prep_w_k(const float* __restrict__ W1l, const float* __restrict__ W1r,
                         const float* __restrict__ W2l, const float* __restrict__ W2r,
                         u16* __restrict__ W1t, u16* __restrict__ W2t) {
  __shared__ float sh[32][33];
  int z = blockIdx.z;
  const float* W;
  u16* Wt;
  int K = 1024, Nc;
  if (z == 0)      { W = W1l; Wt = W1t;                         Nc = 1024; }
  else if (z == 1) { W = W1r; Wt = W1t + (size_t)1024 * 1024;   Nc = 1024; }
  else if (z == 2) { W = W2l; Wt = W2t;                         Nc = 256;  }
  else             { W = W2r; Wt = W2t + (size_t)256 * 1024;    Nc = 256;  }
  int n0 = blockIdx.y * 32;
  if (n0 >= Nc) return;
  int k0 = blockIdx.x * 32;
  int tx = threadIdx.x, ty = threadIdx.y;  // block (32,8)
#pragma unroll
  for (int i = 0; i < 32; i += 8)
    sh[ty + i][tx] = W[(long long)(k0 + ty + i) * Nc + (n0 + tx)];
  __syncthreads();
#pragma unroll
  for (int i = 0; i < 32; i += 8)
    Wt[(long long)(n0 + ty + i) * K + (k0 + tx)] = f2bf(sh[tx][ty + i]);
}

// ---- fused bias concat: bc1 = [b1l|b1r] (2048), bc2 = [b2l|b2r] (512) ------
__global__ void prep_b_k(const float* __restrict__ b1l, const float* __restrict__ b1r,
                         const float* __restrict__ b2l, const float* __restrict__ b2r,
                         float* __restrict__ bc1, float* __restrict__ bc2) {
  int i = blockIdx.x * 256 + threadIdx.x;
  if (i < 1024) bc1[i] = b1l[i];
  else if (i < 2048) bc1[i] = b1r[i - 1024];
  else if (i < 2304) bc2[i - 2048] = b2l[i - 2048];
  else if (i < 2560) bc2[i - 2048] = b2r[i - 2304];
}

// ============ 256x256 BK=64 8-wave phase-interleaved MFMA GEMM ===============
// r4 schedule (best measured over 5 variants — frozen, do not retune).
template <int TN>
__global__ __launch_bounds__(512, 2) void gemm8_k(
    const u16* __restrict__ A, const u16* __restrict__ Bt,
    const float* __restrict__ bias, u16* __restrict__ C, int K) {
  __shared__ u16 As[2][2][8192];
  __shared__ u16 Bs[2][2][8192];
  const int nx = gridDim.x, ny = gridDim.y;
  const int nwg = nx * ny;
  int id = blockIdx.y * nx + blockIdx.x;
  int q = nwg >> 3, r = nwg & 7;
  int xcd = id & 7, loc = id >> 3;
  int sid = (xcd < r ? xcd * (q + 1) : r * (q + 1) + (xcd - r) * q) + loc;
  const int m0 = (sid / ny) * 256;   // n varies fastest within an XCD
  const int n0 = (sid % ny) * 256;

  const int tid = threadIdx.x;
  const int lane = tid & 63;
  const int wave = tid >> 6;
  const int wm = wave >> 2;          // 0..1  (A half)
  const int wn = wave & 3;           // 0..3
  const int bh = wn >> 1;            // B half this wave reads
  const int bql = (wn & 1) * 2048;   // B quarter offset within half (u16)

  const int srow = tid >> 2;         // staging row 0..127
  const int kq   = tid & 3;          // physical k-chunk
  const int ksw  = (kq ^ ((srow >> 1) & 3)) * 8;  // swizzled src col (u16)

  const int nt = K / 64;

  const u16* gA[2] = { A + (long long)(m0 + srow) * K + ksw,
                       A + (long long)(m0 + 128 + srow) * K + ksw };
  const u16* gB[2] = { Bt + (long long)(n0 + srow) * K + ksw,
                       Bt + (long long)(n0 + 128 + srow) * K + ksw };

  auto stageA = [&](int kt, int h) {
    int db = kt & 1;
    gload16(gA[h] + kt * 64,      &As[db][h][tid * 8]);
    gload16(gA[h] + kt * 64 + 32, &As[db][h][4096 + tid * 8]);
  };
  auto stageB = [&](int kt, int h) {
    int db = kt & 1;
    gload16(gB[h] + kt * 64,      &Bs[db][h][tid * 8]);
    gload16(gB[h] + kt * 64 + 32, &Bs[db][h][4096 + tid * 8]);
  };

  const int rbase = (lane & 15) * 32 + (((lane >> 4) ^ ((lane >> 1) & 3)) << 3);

  f32x4 acc[8][4] = {};
  bf16x8 av[4][2], bv[4][2];

  stageA(0, 0); stageA(0, 1); stageB(0, 0); stageB(0, 1);
  if (nt > 1) {
    stageA(1, 0);
    asm volatile("s_waitcnt vmcnt(2)" ::: "memory");
  } else {
    asm volatile("s_waitcnt vmcnt(0)" ::: "memory");
  }
  __builtin_amdgcn_s_barrier();

  for (int t = 0; t < nt; ++t) {
    const int cur = t & 1;
    const u16* Al = &As[cur][wm][0];
    const u16* Bl = &Bs[cur][bh][0];

    // ---- phase 1: Q1 (m 0..3, n 0..1); stage A1(t+1) ----
#pragma unroll
    for (int i = 0; i < 4; ++i) {
      av[i][0] = *(const bf16x8*)(Al + i * 512 + rbase);
      av[i][1] = *(const bf16x8*)(Al + 4096 + i * 512 + rbase);
    }
#pragma unroll
    for (int j = 0; j < 2; ++j) {
      bv[j][0] = *(const bf16x8*)(Bl + bql + j * 512 + rbase);
      bv[j][1] = *(const bf16x8*)(Bl + 4096 + bql + j * 512 + rbase);
    }
    if (t + 1 < nt) stageA(t + 1, 1);
    __builtin_amdgcn_s_barrier();
    __builtin_amdgcn_s_setprio(1);
#pragma unroll
    for (int i = 0; i < 4; ++i)
#pragma unroll
      for (int j = 0; j < 2; ++j) {
        acc[i][j] = __builtin_amdgcn_mfma_f32_16x16x32_bf16(av[i][0], bv[j][0], acc[i][j], 0, 0, 0);
        acc[i][j] = __builtin_amdgcn_mfma_f32_16x16x32_bf16(av[i][1], bv[j][1], acc[i][j], 0, 0, 0);
      }
    __builtin_amdgcn_s_setprio(0);
    __builtin_amdgcn_s_barrier();

    // ---- phase 2: Q2 (m 0..3, n 2..3); stage B0(t+1) ----
#pragma unroll
    for (int j = 2; j < 4; ++j) {
      bv[j][0] = *(const bf16x8*)(Bl + bql + j * 512 + rbase);
      bv[j][1] = *(const bf16x8*)(Bl + 4096 + bql + j * 512 + rbase);
    }
    if (t + 1 < nt) stageB(t + 1, 0);
    __builtin_amdgcn_s_barrier();
    __builtin_amdgcn_s_setprio(1);
#pragma unroll
    for (int i = 0; i < 4; ++i)
#pragma unroll
      for (int j = 2; j < 4; ++j) {
        acc[i][j] = __builtin_amdgcn_mfma_f32_16x16x32_bf16(av[i][0], bv[j][0], acc[i][j], 0, 0, 0);
        acc[i][j] = __builtin_amdgcn_mfma_f32_16x16x32_bf16(av[i][1], bv[j][1], acc[i][j], 0, 0, 0);
      }
    __builtin_amdgcn_s_setprio(0);
    __builtin_amdgcn_s_barrier();

    // ---- phase 3: Q3 (m 4..7, n 2..3); stage B1(t+1) ----
#pragma unroll
    for (int i = 0; i < 4; ++i) {
      av[i][0] = *(const bf16x8*)(Al + (4 + i) * 512 + rbase);
      av[i][1] = *(const bf16x8*)(Al + 4096 + (4 + i) * 512 + rbase);
    }
    if (t + 1 < nt) stageB(t + 1, 1);
    __builtin_amdgcn_s_barrier();
    __builtin_amdgcn_s_setprio(1);
#pragma unroll
    for (int i = 0; i < 4; ++i)
#pragma unroll
      for (int j = 2; j < 4; ++j) {
        acc[4 + i][j] = __builtin_amdgcn_mfma_f32_16x16x32_bf16(av[i][0], bv[j][0], acc[4 + i][j], 0, 0, 0);
        acc[4 + i][j] = __builtin_amdgcn_mfma_f32_16x16x32_bf16(av[i][1], bv[j][1], acc[4 + i][j], 0, 0, 0);
      }
    __builtin_amdgcn_s_setprio(0);
    __builtin_amdgcn_s_barrier();

    // ---- phase 4: Q4 (m 4..7, n 0..1); stage A0(t+2) ----
    if (t + 2 < nt) stageA(t + 2, 0);
    __builtin_amdgcn_s_barrier();
    __builtin_amdgcn_s_setprio(1);
#pragma unroll
    for (int i = 0; i < 4; ++i)
#pragma unroll
      for (int j = 0; j < 2; ++j) {
        acc[4 + i][j] = __builtin_amdgcn_mfma_f32_16x16x32_bf16(av[i][0], bv[j][0], acc[4 + i][j], 0, 0, 0);
        acc[4 + i][j] = __builtin_amdgcn_mfma_f32_16x16x32_bf16(av[i][1], bv[j][1], acc[4 + i][j], 0, 0, 0);
      }
    __builtin_amdgcn_s_setprio(0);
    if (t + 2 < nt) {
      asm volatile("s_waitcnt vmcnt(2)" ::: "memory");
    } else if (t + 1 < nt) {
      asm volatile("s_waitcnt vmcnt(0)" ::: "memory");
    }
    __builtin_amdgcn_s_barrier();
  }

#pragma unroll
  for (int mf = 0; mf < 8; ++mf) {
    int r0 = m0 + wm * 128 + mf * 16 + ((lane >> 4) << 2);
#pragma unroll
    for (int nf = 0; nf < 4; ++nf) {
      int c = n0 + wn * 64 + nf * 16 + (lane & 15);
      float b = bias[c];
#pragma unroll
      for (int j = 0; j < 4; ++j)
        C[(long long)(r0 + j) * TN + c] = f2bf(acc[mf][nf][j] + b);
    }
  }
}

// ---------------- CSR scan / scatter ----------------------------------------
__global__ void blocksum_k(const int* __restrict__ counts, int* __restrict__ bsum, int n) {
  int i = blockIdx.x * 256 + threadIdx.x;
  int v = (i < n) ? counts[i] : 0;
#pragma unroll
  for (int off = 1; off < 64; off <<= 1) v += __shfl_xor(v, off);
  __shared__ int sh[4];
  if ((threadIdx.x & 63) == 0) sh[threadIdx.x >> 6] = v;
  __syncthreads();
  if (threadIdx.x == 0) bsum[blockIdx.x] = sh[0] + sh[1] + sh[2] + sh[3];
}

__global__ void scanb_k(const int* __restrict__ bsum, int* __restrict__ boff,
                        int nb, int* __restrict__ indptr, int n, int E) {
  __shared__ int sh[256];
  int i = threadIdx.x;
  int v = (i < nb) ? bsum[i] : 0;
  sh[i] = v;
  __syncthreads();
  int sum = v;
  for (int off = 1; off < 256; off <<= 1) {
    int t = (i >= off) ? sh[i - off] : 0;
    __syncthreads();
    sum += t;
    sh[i] = sum;
    __syncthreads();
  }
  if (i < nb) boff[i] = sum - v;  // exclusive
  if (i == 0) indptr[n] = E;
}

__global__ void scanf_k(const int* __restrict__ counts, const int* __restrict__ boff,
                        int* __restrict__ indptr, int n) {
  __shared__ int sh[256];
  int b = blockIdx.x;
  int i = b * 256 + threadIdx.x;
  int v = (i < n) ? counts[i] : 0;
  sh[threadIdx.x] = v;
  __syncthreads();
  int sum = v;
  for (int off = 1; off < 256; off <<= 1) {
    int t = (threadIdx.x >= off) ? sh[threadIdx.x - off] : 0;
    __syncthreads();
    sum += t;
    sh[threadIdx.x] = sum;
    __syncthreads();
  }
  if (i < n) indptr[i] = boff[b] + sum - v;
}

__global__ void scatter_k(const int* __restrict__ ei, const int* __restrict__ indptr,
                          int* __restrict__ cursor, int* __restrict__ esrc,
                          int E0, int E) {
  for (int e = blockIdx.x * blockDim.x + threadIdx.x; e < E;
       e += gridDim.x * blockDim.x) {
    int dst, src;
    if (e < E0) { src = ei[e]; dst = ei[E0 + e]; } else { src = dst = e - E0; }
    int pos = atomicAdd(&cursor[dst], 1);
    esrc[indptr[dst] + pos] = src;
  }
}

// ---------------- fused edge layer 1 (H=4): alpha+softmax+agg, online --------
// 6-deep gather ring (lead = 2 pairs ~700cy, covers L3 latency); clamped
// unconditional loads (every dst has a self-loop so pend>p; clamped dup loads
// are provably never consumed).
__global__ __launch_bounds__(256) void fused_edge1_k(
    const u16* __restrict__ XLR, const int* __restrict__ indptr,
    const int* __restrict__ esrc, const float* __restrict__ att,
    const float* __restrict__ bias, u16* __restrict__ X2, int N) {
  int d = blockIdx.x;
  int tid = threadIdx.x;
  int c0 = tid * 4;  // channel in [0,1024); head = tid>>6
  if (d >= N) {
    *(ushort4*)(X2 + (long long)d * C1 + c0) = make_ushort4(0, 0, 0, 0);
    return;
  }
  ushort4 xr4 = *(const ushort4*)(XLR + (long long)d * 2048 + 1024 + c0);
  float xr0 = bf2f(xr4.x), xr1 = bf2f(xr4.y), xr2 = bf2f(xr4.z), xr3 = bf2f(xr4.w);
  float4 at = *(const float4*)(att + c0);

  float m = -INFINITY, l = 0.f;
  float a0 = 0.f, a1 = 0.f, a2 = 0.f, a3 = 0.f;
  int p = indptr[d], pend = indptr[d + 1];
  int pm1 = pend - 1;
#define LD1(ix) (*(const ushort4*)(XLR + (long long)esrc[(ix) < pm1 ? (ix) : pm1] * 2048 + c0))
  ushort4 b0 = LD1(p);
  ushort4 b1 = LD1(p + 1);
  ushort4 b2 = LD1(p + 2);
  ushort4 b3 = LD1(p + 3);
  ushort4 b4 = LD1(p + 4);
  ushort4 b5 = LD1(p + 5);
  int i = p;
  for (; i + 1 < pend; i += 2) {
    ushort4 ca = b0, cb = b1;
    b0 = b2; b1 = b3; b2 = b4; b3 = b5;
    b4 = LD1(i + 6);
    b5 = LD1(i + 7);
    float xa0 = bf2f(ca.x), xa1 = bf2f(ca.y), xa2 = bf2f(ca.z), xa3 = bf2f(ca.w);
    float xb0 = bf2f(cb.x), xb1 = bf2f(cb.y), xb2 = bf2f(cb.z), xb3 = bf2f(cb.w);
    float ta0 = xa0 + xr0, ta1 = xa1 + xr1, ta2 = xa2 + xr2, ta3 = xa3 + xr3;
    float tb0 = xb0 + xr0, tb1 = xb1 + xr1, tb2 = xb2 + xr2, tb3 = xb3 + xr3;
    ta0 = ta0 > 0.f ? ta0 : NEG * ta0;  ta1 = ta1 > 0.f ? ta1 : NEG * ta1;
    ta2 = ta2 > 0.f ? ta2 : NEG * ta2;  ta3 = ta3 > 0.f ? ta3 : NEG * ta3;
    tb0 = tb0 > 0.f ? tb0 : NEG * tb0;  tb1 = tb1 > 0.f ? tb1 : NEG * tb1;
    tb2 = tb2 > 0.f ? tb2 : NEG * tb2;  tb3 = tb3 > 0.f ? tb3 : NEG * tb3;
    float sa = at.x * ta0 + at.y * ta1 + at.z * ta2 + at.w * ta3;
    float sb = at.x * tb0 + at.y * tb1 + at.z * tb2 + at.w * tb3;
#pragma unroll
    for (int off = 1; off < 64; off <<= 1) {
      sa += __shfl_xor(sa, off);
      sb += __shfl_xor(sb, off);
    }
    float mnew = fmaxf(fmaxf(m, sa), sb);
    float scale = __expf(m - mnew);
    float wa = __expf(sa - mnew);
    float wb = __expf(sb - mnew);
    l = l * scale + wa + wb;
    a0 = a0 * scale + wa * xa0 + wb * xb0;
    a1 = a1 * scale + wa * xa1 + wb * xb1;
    a2 = a2 * scale + wa * xa2 + wb * xb2;
    a3 = a3 * scale + wa * xa3 + wb * xb3;
    m = mnew;
  }
  if (i < pend) {  // tail single edge (data in b0)
    float xa0 = bf2f(b0.x), xa1 = bf2f(b0.y), xa2 = bf2f(b0.z), xa3 = bf2f(b0.w);
    float ta0 = xa0 + xr0, ta1 = xa1 + xr1, ta2 = xa2 + xr2, ta3 = xa3 + xr3;
    ta0 = ta0 > 0.f ? ta0 : NEG * ta0;  ta1 = ta1 > 0.f ? ta1 : NEG * ta1;
    ta2 = ta2 > 0.f ? ta2 : NEG * ta2;  ta3 = ta3 > 0.f ? ta3 : NEG * ta3;
    float sa = at.x * ta0 + at.y * ta1 + at.z * ta2 + at.w * ta3;
#pragma unroll
    for (int off = 1; off < 64; off <<= 1) sa += __shfl_xor(sa, off);
    float mnew = fmaxf(m, sa);
    float scale = __expf(m - mnew);
    float wa = __expf(sa - mnew);
    l = l * scale + wa;
    a0 = a0 * scale + wa * xa0;
    a1 = a1 * scale + wa * xa1;
    a2 = a2 * scale + wa * xa2;
    a3 = a3 * scale + wa * xa3;
  }
#undef LD1
  float inv = 1.f / (l + 1e-16f);
  float4 b = *(const float4*)(bias + c0);
  ushort4 o;
  o.x = f2bf(fmaxf(a0 * inv + b.x, 0.f));
  o.y = f2bf(fmaxf(a1 * inv + b.y, 0.f));
  o.z = f2bf(fmaxf(a2 * inv + b.z, 0.f));
  o.w = f2bf(fmaxf(a3 * inv + b.w, 0.f));
  *(ushort4*)(X2 + (long long)d * C1 + c0) = o;
}

// ---------------- fused edge layer 2 (H=1): one wave per dst, f32 out --------
__global__ __launch_bounds__(256) void fused_edge2_k(
    const u16* __restrict__ XLR, const int* __restrict__ indptr,
    const int* __restrict__ esrc, const float* __restrict__ att,
    const float* __restrict__ bias, float* __restrict__ out, int N) {
  int d = blockIdx.x * 4 + (threadIdx.x >> 6);
  if (d >= N) return;
  int lane = threadIdx.x & 63;
  int c0 = lane * 4;
  ushort4 xr4 = *(const ushort4*)(XLR + (long long)d * 512 + 256 + c0);
  float xr0 = bf2f(xr4.x), xr1 = bf2f(xr4.y), xr2 = bf2f(xr4.z), xr3 = bf2f(xr4.w);
  float4 at = *(const float4*)(att + c0);

  float m = -INFINITY, l = 0.f;
  float a0 = 0.f, a1 = 0.f, a2 = 0.f, a3 = 0.f;
  int p = indptr[d], pend = indptr[d + 1];
  int pm1 = pend - 1;
#define LD2(ix) (*(const ushort4*)(XLR + (long long)esrc[(ix) < pm1 ? (ix) : pm1] * 512 + c0))
  ushort4 b0 = LD2(p);
  ushort4 b1 = LD2(p + 1);
  ushort4 b2 = LD2(p + 2);
  ushort4 b3 = LD2(p + 3);
  ushort4 b4 = LD2(p + 4);
  ushort4 b5 = LD2(p + 5);
  int i = p;
  for (; i + 1 < pend; i += 2) {
    ushort4 ca = b0, cb = b1;
    b0 = b2; b1 = b3; b2 = b4; b3 = b5;
    b4 = LD2(i + 6);
    b5 = LD2(i + 7);
    float xa0 = bf2f(ca.x), xa1 = bf2f(ca.y), xa2 = bf2f(ca.z), xa3 = bf2f(ca.w);
    float xb0 = bf2f(cb.x), xb1 = bf2f(cb.y), xb2 = bf2f(cb.z), xb3 = bf2f(cb.w);
    float ta0 = xa0 + xr0, ta1 = xa1 + xr1, ta2 = xa2 + xr2, ta3 = xa3 + xr3;
    float tb0 = xb0 + xr0, tb1 = xb1 + xr1, tb2 = xb2 + xr2, tb3 = xb3 + xr3;
    ta0 = ta0 > 0.f ? ta0 : NEG * ta0;  ta1 = ta1 > 0.f ? ta1 : NEG * ta1;
    ta2 = ta2 > 0.f ? ta2 : NEG * ta2;  ta3 = ta3 > 0.f ? ta3 : NEG * ta3;
    tb0 = tb0 > 0.f ? tb0 : NEG * tb0;  tb1 = tb1 > 0.f ? tb1 : NEG * tb1;
    tb2 = tb2 > 0.f ? tb2 : NEG * tb2;  tb3 = tb3 > 0.f ? tb3 : NEG * tb3;
    float sa = at.x * ta0 + at.y * ta1 + at.z * ta2 + at.w * ta3;
    float sb = at.x * tb0 + at.y * tb1 + at.z * tb2 + at.w * tb3;
#pragma unroll
    for (int off = 1; off < 64; off <<= 1) {
      sa += __shfl_xor(sa, off);
      sb += __shfl_xor(sb, off);
    }
    float mnew = fmaxf(fmaxf(m, sa), sb);
    float scale = __expf(m - mnew);
    float wa = __expf(sa - mnew);
    float wb = __expf(sb - mnew);
    l = l * scale + wa + wb;
    a0 = a0 * scale + wa * xa0 + wb * xb0;
    a1 = a1 * scale + wa * xa1 + wb * xb1;
    a2 = a2 * scale + wa * xa2 + wb * xb2;
    a3 = a3 * scale + wa * xa3 + wb * xb3;
    m = mnew;
  }
  if (i < pend) {
    float xa0 = bf2f(b0.x), xa1 = bf2f(b0.y), xa2 = bf2f(b0.z), xa3 = bf2f(b0.w);
    float ta0 = xa0 + xr0, ta1 = xa1 + xr1, ta2 = xa2 + xr2, ta3 = xa3 + xr3;
    ta0 = ta0 > 0.f ? ta0 : NEG * ta0;  ta1 = ta1 > 0.f ? ta1 : NEG * ta1;
    ta2 = ta2 > 0.f ? ta2 : NEG * ta2;  ta3 = ta3 > 0.f ? ta3 : NEG * ta3;
    float sa = at.x * ta0 + at.y * ta1 + at.z * ta2 + at.w * ta3;
#pragma unroll
    for (int off = 1; off < 64; off <<= 1) sa += __shfl_xor(sa, off);
    float mnew = fmaxf(m, sa);
    float scale = __expf(m - mnew);
    float wa = __expf(sa - mnew);
    l = l * scale + wa;
    a0 = a0 * scale + wa * xa0;
    a1 = a1 * scale + wa * xa1;
    a2 = a2 * scale + wa * xa2;
    a3 = a3 * scale + wa * xa3;
  }
#undef LD2
  float inv = 1.f / (l + 1e-16f);
  float4 b = *(const float4*)(bias + c0);
  float4 o;
  o.x = fmaxf(a0 * inv + b.x, 0.f);
  o.y = fmaxf(a1 * inv + b.y, 0.f);
  o.z = fmaxf(a2 * inv + b.z, 0.f);
  o.w = fmaxf(a3 * inv + b.w, 0.f);
  *(float4*)(out + (long long)d * C2 + c0) = o;
}

// =============================================================================
extern "C" void kernel_launch(void* const* d_in, const int* in_sizes, int n_in,
                              void* d_out, int out_size, void* d_ws, size_t ws_size,
                              hipStream_t stream) {
  const float* x     = (const float*)d_in[0];
  const int*   ei    = (const int*)d_in[1];
  const float* W1l   = (const float*)d_in[2];
  const float* b1l   = (const float*)d_in[3];
  const float* W1r   = (const float*)d_in[4];
  const float* b1r   = (const float*)d_in[5];
  const float* att1  = (const float*)d_in[6];
  const float* bias1 = (const float*)d_in[7];
  const float* W2l   = (const float*)d_in[8];
  const float* b2l   = (const float*)d_in[9];
  const float* W2r   = (const float*)d_in[10];
  const float* b2r   = (const float*)d_in[11];
  const float* att2  = (const float*)d_in[12];
  const float* bias2 = (const float*)d_in[13];

  const int N  = in_sizes[0] / D_IN;  // 50000
  const int E0 = in_sizes[1] / 2;     // 400000
  const int E  = E0 + N;              // with self-loops
  const int Mp = (N + 255) & ~255;    // 50176 (multiple of 256)
  const int NB = (N + 255) / 256;     // scan blocks (196)

  char* p = (char*)d_ws;
  auto alloc = [&](size_t bytes) -> char* {
    char* r = p;
    p += (bytes + 255) & ~(size_t)255;
    return r;
  };
  u16* A_bf  = (u16*)alloc((size_t)Mp * D_IN * 2);   // x bf16; later X2 (layer-2 A)
  u16* XLR1  = (u16*)alloc((size_t)Mp * 2048 * 2);   // [xl|xr] layer 1; later XLR2
  u16* W1t   = (u16*)alloc((size_t)2048 * D_IN * 2);
  u16* W2t   = (u16*)alloc((size_t)512 * C1 * 2);
  float* bc1 = (float*)alloc(2048 * 4);
  float* bc2 = (float*)alloc(512 * 4);
  int* counts = (int*)alloc((size_t)N * 4);          // counts+cursor adjacent:
  int* cursor = (int*)alloc((size_t)N * 4);          //  single memset covers both
  int* indptr = (int*)alloc((size_t)(N + 1) * 4);
  int* esrc   = (int*)alloc((size_t)E * 4);
  int* bsum   = (int*)alloc((size_t)NB * 4);
  int* boff   = (int*)alloc((size_t)NB * 4);
  u16* X2   = A_bf;   // alias: A_bf dead after GEMM1
  u16* XLR2 = XLR1;   // alias: XLR1 dead after fused_edge1

  size_t need = (size_t)(p - (char*)d_ws);
  if (ws_size < need) {
    hipMemsetAsync(d_out, 0xFF, 4, stream);  // NaN sentinel
    return;
  }

  // one memset over counts..cursor (contiguous in the arena)
  hipMemsetAsync(counts, 0, (size_t)((char*)cursor - (char*)counts) + (size_t)N * 4,
                 stream);

  // ---- prep: fused cast_x+count, W transposes, bias concats ----
  {
    long long tot = (long long)Mp * (D_IN / 8);
    int CB = (int)((tot + 255) / 256);
    cast_count_k<<<CB + 1024, 256, 0, stream>>>(x, A_bf, N, Mp, CB, ei, counts, E0, E);
  }
  prep_w_k<<<dim3(32, 32, 4), dim3(32, 8), 0, stream>>>(W1l, W1r, W2l, W2r, W1t, W2t);
  prep_b_k<<<10, 256, 0, stream>>>(b1l, b1r, b2l, b2r, bc1, bc2);

  // ---- CSR by dst (shared by both layers) ----
  blocksum_k<<<NB, 256, 0, stream>>>(counts, bsum, N);
  scanb_k<<<1, 256, 0, stream>>>(bsum, boff, NB, indptr, N, E);
  scanf_k<<<NB, 256, 0, stream>>>(counts, boff, indptr, N);
  scatter_k<<<1024, 256, 0, stream>>>(ei, indptr, cursor, esrc, E0, E);

  // ---- layer 1 ----
  gemm8_k<2048><<<dim3(Mp / 256, 2048 / 256), 512, 0, stream>>>(A_bf, W1t, bc1, XLR1, D_IN);
  fused_edge1_k<<<Mp, 256, 0, stream>>>(XLR1, indptr, esrc, att1, bias1, X2, N);

  // ---- layer 2 ----
  gemm8_k<512><<<dim3(Mp / 256, 512 / 256), 512, 0, stream>>>(X2, W2t, bc2, XLR2, C1);
  fused_edge2_k<<<(N + 3) / 4, 256, 0, stream>>>(XLR2, indptr, esrc, att2, bias2,
                                                 (float*)d_out, N);
}

// Round 11
// 651.388 us; speedup vs baseline: 1.2125x; 1.0128x over previous
//
#include <hip/hip_runtime.h>
#include <stdint.h>

#define D_IN 1024
#define C1   1024   // H1*HID
#define C2   256    // H2*HID
#define NEG  0.2f

typedef unsigned int u32;
typedef uint16_t u16;
typedef __attribute__((ext_vector_type(8))) short bf16x8;
typedef __attribute__((ext_vector_type(4))) float f32x4;

__device__ __forceinline__ float bf2f(u32 lo16) { return __uint_as_float(lo16 << 16); }
__device__ __forceinline__ u16 f2bf(float f) {
  u32 u = __float_as_uint(f);
  u += 0x7fffu + ((u >> 16) & 1u);   // RNE
  return (u16)(u >> 16);
}

__device__ __forceinline__ void gload16(const u16* g, u16* l) {
  __builtin_amdgcn_global_load_lds(
      (const __attribute__((address_space(1))) unsigned int*)g,
      (__attribute__((address_space(3))) unsigned int*)l,
      16, 0, 0);
}

// ==== single prep dispatch: cast_x | 4x transpose+cast | bias concat | count
// Block ranges (all 256-thread 1D blocks; branch is block-uniform):
//   [0, CB)                 : cast x f32 -> padded bf16 A
//   [CB, CB+2560)           : 32x32 transpose tiles (W1l 1024 | W1r 1024 |
//                             W2l 256 | W2r 256)
//   [CB+2560, CB+2570)      : bias concats
//   [CB+2570, CB+2570+1024) : edge count (grid-stride)
__global__ void prep_all_k(const float* __restrict__ x, u16* __restrict__ A,
                           int nrows, int Mp, int CB,
                           const float* __restrict__ W1l, const float* __restrict__ W1r,
                           const float* __restrict__ W2l, const float* __restrict__ W2r,
                           u16* __restrict__ W1t, u16* __restrict__ W2t,
                           const float* __restrict__ b1l, const float* __restrict__ b1r,
                           const float* __restrict__ b2l, const float* __restrict__ b2r,
                           float* __restrict__ bc1, float* __restrict__ bc2,
                           const int* __restrict__ ei, int* __restrict__ counts,
                           int E0, int E) {
  int bid = blockIdx.x;
  if (bid < CB) {
    // ---- cast x -> bf16 A, zero pad rows ----
    long long idx = (long long)bid * 256 + threadIdx.x;
    long long total = (long long)Mp * (D_IN / 8);
    if (idx >= total) return;
    long long base = idx * 8;
    int row = (int)(base >> 10);  // D_IN==1024
    u32 o0 = 0, o1 = 0, o2 = 0, o3 = 0;
    if (row < nrows) {
      const float4* px = (const float4*)(x + base);
      float4 v0 = px[0], v1 = px[1];
      o0 = (u32)f2bf(v0.x) | ((u32)f2bf(v0.y) << 16);
      o1 = (u32)f2bf(v0.z) | ((u32)f2bf(v0.w) << 16);
      o2 = (u32)f2bf(v1.x) | ((u32)f2bf(v1.y) << 16);
      o3 = (u32)f2bf(v1.z) | ((u32)f2bf(v1.w) << 16);
    }
    *(uint4*)(A + base) = make_uint4(o0, o1, o2, o3);
    return;
  }
  bid -= CB;
  if (bid < 2560) {
    // ---- transpose+cast one 32x32 tile ----
    __shared__ float sh[32][33];
    const float* W;
    u16* Wt;
    int Nc, tile;
    if (bid < 1024)      { W = W1l; Wt = W1t;                       Nc = 1024; tile = bid; }
    else if (bid < 2048) { W = W1r; Wt = W1t + (size_t)1024 * 1024; Nc = 1024; tile = bid - 1024; }
    else if (bid < 2304) { W = W2l; Wt = W2t;                       Nc = 256;  tile = bid - 2048; }
    else                 { W = W2r; Wt = W2t + (size_t)256 * 1024;  Nc = 256;  tile = bid - 2304; }
    int ntx = Nc / 32;                 // tiles along Nc
    int k0 = (tile / ntx) * 32;
    int n0 = (tile % ntx) * 32;
    int tx = threadIdx.x & 31, ty = threadIdx.x >> 5;  // (32,8)
#pragma unroll
    for (int i = 0; i < 32; i += 8)
      sh[ty + i][tx] = W[(long long)(k0 + ty + i) * Nc + (n0 + tx)];
    __syncthreads();
#pragma unroll
    for (int i = 0; i < 32; i += 8)
      Wt[(long long)(n0 + ty + i) * 1024 + (k0 + tx)] = f2bf(sh[tx][ty + i]);
    return;
  }
  bid -= 2560;
  if (bid < 10) {
    int i = bid * 256 + threadIdx.x;
    if (i < 1024) bc1[i] = b1l[i];
    else if (i < 2048) bc1[i] = b1r[i - 1024];
    else if (i < 2304) bc2[i - 2048] = b2l[i - 2048];
    else if (i < 2560) bc2[i - 2048] = b2r[i - 2304];
    return;
  }
  bid -= 10;
  // ---- edge count ----
  for (int e = bid * 256 + threadIdx.x; e < E; e += 1024 * 256) {
    int dst = (e < E0) ? ei[E0 + e] : e - E0;
    atomicAdd(&counts[dst], 1);
  }
}

// ============ 256x256 BK=64 8-wave phase-interleaved MFMA GEMM ===============
// r4 schedule (best measured over 5 variants — frozen, do not retune).
template <int TN>
__global__ __launch_bounds__(512, 2) void gemm8_k(
    const u16* __restrict__ A, const u16* __restrict__ Bt,
    const float* __restrict__ bias, u16* __restrict__ C, int K) {
  __shared__ u16 As[2][2][8192];
  __shared__ u16 Bs[2][2][8192];
  const int nx = gridDim.x, ny = gridDim.y;
  const int nwg = nx * ny;
  int id = blockIdx.y * nx + blockIdx.x;
  int q = nwg >> 3, r = nwg & 7;
  int xcd = id & 7, loc = id >> 3;
  int sid = (xcd < r ? xcd * (q + 1) : r * (q + 1) + (xcd - r) * q) + loc;
  const int m0 = (sid / ny) * 256;   // n varies fastest within an XCD
  const int n0 = (sid % ny) * 256;

  const int tid = threadIdx.x;
  const int lane = tid & 63;
  const int wave = tid >> 6;
  const int wm = wave >> 2;          // 0..1  (A half)
  const int wn = wave & 3;           // 0..3
  const int bh = wn >> 1;            // B half this wave reads
  const int bql = (wn & 1) * 2048;   // B quarter offset within half (u16)

  const int srow = tid >> 2;         // staging row 0..127
  const int kq   = tid & 3;          // physical k-chunk
  const int ksw  = (kq ^ ((srow >> 1) & 3)) * 8;  // swizzled src col (u16)

  const int nt = K / 64;

  const u16* gA[2] = { A + (long long)(m0 + srow) * K + ksw,
                       A + (long long)(m0 + 128 + srow) * K + ksw };
  const u16* gB[2] = { Bt + (long long)(n0 + srow) * K + ksw,
                       Bt + (long long)(n0 + 128 + srow) * K + ksw };

  auto stageA = [&](int kt, int h) {
    int db = kt & 1;
    gload16(gA[h] + kt * 64,      &As[db][h][tid * 8]);
    gload16(gA[h] + kt * 64 + 32, &As[db][h][4096 + tid * 8]);
  };
  auto stageB = [&](int kt, int h) {
    int db = kt & 1;
    gload16(gB[h] + kt * 64,      &Bs[db][h][tid * 8]);
    gload16(gB[h] + kt * 64 + 32, &Bs[db][h][4096 + tid * 8]);
  };

  const int rbase = (lane & 15) * 32 + (((lane >> 4) ^ ((lane >> 1) & 3)) << 3);

  f32x4 acc[8][4] = {};
  bf16x8 av[4][2], bv[4][2];

  stageA(0, 0); stageA(0, 1); stageB(0, 0); stageB(0, 1);
  if (nt > 1) {
    stageA(1, 0);
    asm volatile("s_waitcnt vmcnt(2)" ::: "memory");
  } else {
    asm volatile("s_waitcnt vmcnt(0)" ::: "memory");
  }
  __builtin_amdgcn_s_barrier();

  for (int t = 0; t < nt; ++t) {
    const int cur = t & 1;
    const u16* Al = &As[cur][wm][0];
    const u16* Bl = &Bs[cur][bh][0];

    // ---- phase 1: Q1 (m 0..3, n 0..1); stage A1(t+1) ----
#pragma unroll
    for (int i = 0; i < 4; ++i) {
      av[i][0] = *(const bf16x8*)(Al + i * 512 + rbase);
      av[i][1] = *(const bf16x8*)(Al + 4096 + i * 512 + rbase);
    }
#pragma unroll
    for (int j = 0; j < 2; ++j) {
      bv[j][0] = *(const bf16x8*)(Bl + bql + j * 512 + rbase);
      bv[j][1] = *(const bf16x8*)(Bl + 4096 + bql + j * 512 + rbase);
    }
    if (t + 1 < nt) stageA(t + 1, 1);
    __builtin_amdgcn_s_barrier();
    __builtin_amdgcn_s_setprio(1);
#pragma unroll
    for (int i = 0; i < 4; ++i)
#pragma unroll
      for (int j = 0; j < 2; ++j) {
        acc[i][j] = __builtin_amdgcn_mfma_f32_16x16x32_bf16(av[i][0], bv[j][0], acc[i][j], 0, 0, 0);
        acc[i][j] = __builtin_amdgcn_mfma_f32_16x16x32_bf16(av[i][1], bv[j][1], acc[i][j], 0, 0, 0);
      }
    __builtin_amdgcn_s_setprio(0);
    __builtin_amdgcn_s_barrier();

    // ---- phase 2: Q2 (m 0..3, n 2..3); stage B0(t+1) ----
#pragma unroll
    for (int j = 2; j < 4; ++j) {
      bv[j][0] = *(const bf16x8*)(Bl + bql + j * 512 + rbase);
      bv[j][1] = *(const bf16x8*)(Bl + 4096 + bql + j * 512 + rbase);
    }
    if (t + 1 < nt) stageB(t + 1, 0);
    __builtin_amdgcn_s_barrier();
    __builtin_amdgcn_s_setprio(1);
#pragma unroll
    for (int i = 0; i < 4; ++i)
#pragma unroll
      for (int j = 2; j < 4; ++j) {
        acc[i][j] = __builtin_amdgcn_mfma_f32_16x16x32_bf16(av[i][0], bv[j][0], acc[i][j], 0, 0, 0);
        acc[i][j] = __builtin_amdgcn_mfma_f32_16x16x32_bf16(av[i][1], bv[j][1], acc[i][j], 0, 0, 0);
      }
    __builtin_amdgcn_s_setprio(0);
    __builtin_amdgcn_s_barrier();

    // ---- phase 3: Q3 (m 4..7, n 2..3); stage B1(t+1) ----
#pragma unroll
    for (int i = 0; i < 4; ++i) {
      av[i][0] = *(const bf16x8*)(Al + (4 + i) * 512 + rbase);
      av[i][1] = *(const bf16x8*)(Al + 4096 + (4 + i) * 512 + rbase);
    }
    if (t + 1 < nt) stageB(t + 1, 1);
    __builtin_amdgcn_s_barrier();
    __builtin_amdgcn_s_setprio(1);
#pragma unroll
    for (int i = 0; i < 4; ++i)
#pragma unroll
      for (int j = 2; j < 4; ++j) {
        acc[4 + i][j] = __builtin_amdgcn_mfma_f32_16x16x32_bf16(av[i][0], bv[j][0], acc[4 + i][j], 0, 0, 0);
        acc[4 + i][j] = __builtin_amdgcn_mfma_f32_16x16x32_bf16(av[i][1], bv[j][1], acc[4 + i][j], 0, 0, 0);
      }
    __builtin_amdgcn_s_setprio(0);
    __builtin_amdgcn_s_barrier();

    // ---- phase 4: Q4 (m 4..7, n 0..1); stage A0(t+2) ----
    if (t + 2 < nt) stageA(t + 2, 0);
    __builtin_amdgcn_s_barrier();
    __builtin_amdgcn_s_setprio(1);
#pragma unroll
    for (int i = 0; i < 4; ++i)
#pragma unroll
      for (int j = 0; j < 2; ++j) {
        acc[4 + i][j] = __builtin_amdgcn_mfma_f32_16x16x32_bf16(av[i][0], bv[j][0], acc[4 + i][j], 0, 0, 0);
        acc[4 + i][j] = __builtin_amdgcn_mfma_f32_16x16x32_bf16(av[i][1], bv[j][1], acc[4 + i][j], 0, 0, 0);
      }
    __builtin_amdgcn_s_setprio(0);
    if (t + 2 < nt) {
      asm volatile("s_waitcnt vmcnt(2)" ::: "memory");
    } else if (t + 1 < nt) {
      asm volatile("s_waitcnt vmcnt(0)" ::: "memory");
    }
    __builtin_amdgcn_s_barrier();
  }

#pragma unroll
  for (int mf = 0; mf < 8; ++mf) {
    int r0 = m0 + wm * 128 + mf * 16 + ((lane >> 4) << 2);
#pragma unroll
    for (int nf = 0; nf < 4; ++nf) {
      int c = n0 + wn * 64 + nf * 16 + (lane & 15);
      float b = bias[c];
#pragma unroll
      for (int j = 0; j < 4; ++j)
        C[(long long)(r0 + j) * TN + c] = f2bf(acc[mf][nf][j] + b);
    }
  }
}

// ---------------- CSR scan / scatter ----------------------------------------
__global__ void blocksum_k(const int* __restrict__ counts, int* __restrict__ bsum, int n) {
  int i = blockIdx.x * 256 + threadIdx.x;
  int v = (i < n) ? counts[i] : 0;
#pragma unroll
  for (int off = 1; off < 64; off <<= 1) v += __shfl_xor(v, off);
  __shared__ int sh[4];
  if ((threadIdx.x & 63) == 0) sh[threadIdx.x >> 6] = v;
  __syncthreads();
  if (threadIdx.x == 0) bsum[blockIdx.x] = sh[0] + sh[1] + sh[2] + sh[3];
}

__global__ void scanb_k(const int* __restrict__ bsum, int* __restrict__ boff,
                        int nb, int* __restrict__ indptr, int n, int E) {
  __shared__ int sh[256];
  int i = threadIdx.x;
  int v = (i < nb) ? bsum[i] : 0;
  sh[i] = v;
  __syncthreads();
  int sum = v;
  for (int off = 1; off < 256; off <<= 1) {
    int t = (i >= off) ? sh[i - off] : 0;
    __syncthreads();
    sum += t;
    sh[i] = sum;
    __syncthreads();
  }
  if (i < nb) boff[i] = sum - v;  // exclusive
  if (i == 0) indptr[n] = E;
}

__global__ void scanf_k(const int* __restrict__ counts, const int* __restrict__ boff,
                        int* __restrict__ indptr, int n) {
  __shared__ int sh[256];
  int b = blockIdx.x;
  int i = b * 256 + threadIdx.x;
  int v = (i < n) ? counts[i] : 0;
  sh[threadIdx.x] = v;
  __syncthreads();
  int sum = v;
  for (int off = 1; off < 256; off <<= 1) {
    int t = (threadIdx.x >= off) ? sh[threadIdx.x - off] : 0;
    __syncthreads();
    sum += t;
    sh[threadIdx.x] = sum;
    __syncthreads();
  }
  if (i < n) indptr[i] = boff[b] + sum - v;
}

__global__ void scatter_k(const int* __restrict__ ei, const int* __restrict__ indptr,
                          int* __restrict__ cursor, int* __restrict__ esrc,
                          int E0, int E) {
  for (int e = blockIdx.x * blockDim.x + threadIdx.x; e < E;
       e += gridDim.x * blockDim.x) {
    int dst, src;
    if (e < E0) { src = ei[e]; dst = ei[E0 + e]; } else { src = dst = e - E0; }
    int pos = atomicAdd(&cursor[dst], 1);
    esrc[indptr[dst] + pos] = src;
  }
}

// ---------------- fused edge layer 1 (H=4): alpha+softmax+agg, online --------
// 6-deep gather ring; clamped unconditional loads (self-loop => pend>p).
__global__ __launch_bounds__(256) void fused_edge1_k(
    const u16* __restrict__ XLR, const int* __restrict__ indptr,
    const int* __restrict__ esrc, const float* __restrict__ att,
    const float* __restrict__ bias, u16* __restrict__ X2, int N) {
  int d = blockIdx.x;
  int tid = threadIdx.x;
  int c0 = tid * 4;  // channel in [0,1024); head = tid>>6
  if (d >= N) {
    *(ushort4*)(X2 + (long long)d * C1 + c0) = make_ushort4(0, 0, 0, 0);
    return;
  }
  ushort4 xr4 = *(const ushort4*)(XLR + (long long)d * 2048 + 1024 + c0);
  float xr0 = bf2f(xr4.x), xr1 = bf2f(xr4.y), xr2 = bf2f(xr4.z), xr3 = bf2f(xr4.w);
  float4 at = *(const float4*)(att + c0);

  float m = -INFINITY, l = 0.f;
  float a0 = 0.f, a1 = 0.f, a2 = 0.f, a3 = 0.f;
  int p = indptr[d], pend = indptr[d + 1];
  int pm1 = pend - 1;
#define LD1(ix) (*(const ushort4*)(XLR + (long long)esrc[(ix) < pm1 ? (ix) : pm1] * 2048 + c0))
  ushort4 b0 = LD1(p);
  ushort4 b1 = LD1(p + 1);
  ushort4 b2 = LD1(p + 2);
  ushort4 b3 = LD1(p + 3);
  ushort4 b4 = LD1(p + 4);
  ushort4 b5 = LD1(p + 5);
  int i = p;
  for (; i + 1 < pend; i += 2) {
    ushort4 ca = b0, cb = b1;
    b0 = b2; b1 = b3; b2 = b4; b3 = b5;
    b4 = LD1(i + 6);
    b5 = LD1(i + 7);
    float xa0 = bf2f(ca.x), xa1 = bf2f(ca.y), xa2 = bf2f(ca.z), xa3 = bf2f(ca.w);
    float xb0 = bf2f(cb.x), xb1 = bf2f(cb.y), xb2 = bf2f(cb.z), xb3 = bf2f(cb.w);
    float ta0 = xa0 + xr0, ta1 = xa1 + xr1, ta2 = xa2 + xr2, ta3 = xa3 + xr3;
    float tb0 = xb0 + xr0, tb1 = xb1 + xr1, tb2 = xb2 + xr2, tb3 = xb3 + xr3;
    ta0 = ta0 > 0.f ? ta0 : NEG * ta0;  ta1 = ta1 > 0.f ? ta1 : NEG * ta1;
    ta2 = ta2 > 0.f ? ta2 : NEG * ta2;  ta3 = ta3 > 0.f ? ta3 : NEG * ta3;
    tb0 = tb0 > 0.f ? tb0 : NEG * tb0;  tb1 = tb1 > 0.f ? tb1 : NEG * tb1;
    tb2 = tb2 > 0.f ? tb2 : NEG * tb2;  tb3 = tb3 > 0.f ? tb3 : NEG * tb3;
    float sa = at.x * ta0 + at.y * ta1 + at.z * ta2 + at.w * ta3;
    float sb = at.x * tb0 + at.y * tb1 + at.z * tb2 + at.w * tb3;
#pragma unroll
    for (int off = 1; off < 64; off <<= 1) {
      sa += __shfl_xor(sa, off);
      sb += __shfl_xor(sb, off);
    }
    float mnew = fmaxf(fmaxf(m, sa), sb);
    float scale = __expf(m - mnew);
    float wa = __expf(sa - mnew);
    float wb = __expf(sb - mnew);
    l = l * scale + wa + wb;
    a0 = a0 * scale + wa * xa0 + wb * xb0;
    a1 = a1 * scale + wa * xa1 + wb * xb1;
    a2 = a2 * scale + wa * xa2 + wb * xb2;
    a3 = a3 * scale + wa * xa3 + wb * xb3;
    m = mnew;
  }
  if (i < pend) {  // tail single edge (data in b0)
    float xa0 = bf2f(b0.x), xa1 = bf2f(b0.y), xa2 = bf2f(b0.z), xa3 = bf2f(b0.w);
    float ta0 = xa0 + xr0, ta1 = xa1 + xr1, ta2 = xa2 + xr2, ta3 = xa3 + xr3;
    ta0 = ta0 > 0.f ? ta0 : NEG * ta0;  ta1 = ta1 > 0.f ? ta1 : NEG * ta1;
    ta2 = ta2 > 0.f ? ta2 : NEG * ta2;  ta3 = ta3 > 0.f ? ta3 : NEG * ta3;
    float sa = at.x * ta0 + at.y * ta1 + at.z * ta2 + at.w * ta3;
#pragma unroll
    for (int off = 1; off < 64; off <<= 1) sa += __shfl_xor(sa, off);
    float mnew = fmaxf(m, sa);
    float scale = __expf(m - mnew);
    float wa = __expf(sa - mnew);
    l = l * scale + wa;
    a0 = a0 * scale + wa * xa0;
    a1 = a1 * scale + wa * xa1;
    a2 = a2 * scale + wa * xa2;
    a3 = a3 * scale + wa * xa3;
  }
#undef LD1
  float inv = 1.f / (l + 1e-16f);
  float4 b = *(const float4*)(bias + c0);
  ushort4 o;
  o.x = f2bf(fmaxf(a0 * inv + b.x, 0.f));
  o.y = f2bf(fmaxf(a1 * inv + b.y, 0.f));
  o.z = f2bf(fmaxf(a2 * inv + b.z, 0.f));
  o.w = f2bf(fmaxf(a3 * inv + b.w, 0.f));
  *(ushort4*)(X2 + (long long)d * C1 + c0) = o;
}

// ---------------- fused edge layer 2 (H=1): one wave per dst, f32 out --------
__global__ __launch_bounds__(256) void fused_edge2_k(
    const u16* __restrict__ XLR, const int* __restrict__ indptr,
    const int* __restrict__ esrc, const float* __restrict__ att,
    const float* __restrict__ bias, float* __restrict__ out, int N) {
  int d = blockIdx.x * 4 + (threadIdx.x >> 6);
  if (d >= N) return;
  int lane = threadIdx.x & 63;
  int c0 = lane * 4;
  ushort4 xr4 = *(const ushort4*)(XLR + (long long)d * 512 + 256 + c0);
  float xr0 = bf2f(xr4.x), xr1 = bf2f(xr4.y), xr2 = bf2f(xr4.z), xr3 = bf2f(xr4.w);
  float4 at = *(const float4*)(att + c0);

  float m = -INFINITY, l = 0.f;
  float a0 = 0.f, a1 = 0.f, a2 = 0.f, a3 = 0.f;
  int p = indptr[d], pend = indptr[d + 1];
  int pm1 = pend - 1;
#define LD2(ix) (*(const ushort4*)(XLR + (long long)esrc[(ix) < pm1 ? (ix) : pm1] * 512 + c0))
  ushort4 b0 = LD2(p);
  ushort4 b1 = LD2(p + 1);
  ushort4 b2 = LD2(p + 2);
  ushort4 b3 = LD2(p + 3);
  ushort4 b4 = LD2(p + 4);
  ushort4 b5 = LD2(p + 5);
  int i = p;
  for (; i + 1 < pend; i += 2) {
    ushort4 ca = b0, cb = b1;
    b0 = b2; b1 = b3; b2 = b4; b3 = b5;
    b4 = LD2(i + 6);
    b5 = LD2(i + 7);
    float xa0 = bf2f(ca.x), xa1 = bf2f(ca.y), xa2 = bf2f(ca.z), xa3 = bf2f(ca.w);
    float xb0 = bf2f(cb.x), xb1 = bf2f(cb.y), xb2 = bf2f(cb.z), xb3 = bf2f(cb.w);
    float ta0 = xa0 + xr0, ta1 = xa1 + xr1, ta2 = xa2 + xr2, ta3 = xa3 + xr3;
    float tb0 = xb0 + xr0, tb1 = xb1 + xr1, tb2 = xb2 + xr2, tb3 = xb3 + xr3;
    ta0 = ta0 > 0.f ? ta0 : NEG * ta0;  ta1 = ta1 > 0.f ? ta1 : NEG * ta1;
    ta2 = ta2 > 0.f ? ta2 : NEG * ta2;  ta3 = ta3 > 0.f ? ta3 : NEG * ta3;
    tb0 = tb0 > 0.f ? tb0 : NEG * tb0;  tb1 = tb1 > 0.f ? tb1 : NEG * tb1;
    tb2 = tb2 > 0.f ? tb2 : NEG * tb2;  tb3 = tb3 > 0.f ? tb3 : NEG * tb3;
    float sa = at.x * ta0 + at.y * ta1 + at.z * ta2 + at.w * ta3;
    float sb = at.x * tb0 + at.y * tb1 + at.z * tb2 + at.w * tb3;
#pragma unroll
    for (int off = 1; off < 64; off <<= 1) {
      sa += __shfl_xor(sa, off);
      sb += __shfl_xor(sb, off);
    }
    float mnew = fmaxf(fmaxf(m, sa), sb);
    float scale = __expf(m - mnew);
    float wa = __expf(sa - mnew);
    float wb = __expf(sb - mnew);
    l = l * scale + wa + wb;
    a0 = a0 * scale + wa * xa0 + wb * xb0;
    a1 = a1 * scale + wa * xa1 + wb * xb1;
    a2 = a2 * scale + wa * xa2 + wb * xb2;
    a3 = a3 * scale + wa * xa3 + wb * xb3;
    m = mnew;
  }
  if (i < pend) {
    float xa0 = bf2f(b0.x), xa1 = bf2f(b0.y), xa2 = bf2f(b0.z), xa3 = bf2f(b0.w);
    float ta0 = xa0 + xr0, ta1 = xa1 + xr1, ta2 = xa2 + xr2, ta3 = xa3 + xr3;
    ta0 = ta0 > 0.f ? ta0 : NEG * ta0;  ta1 = ta1 > 0.f ? ta1 : NEG * ta1;
    ta2 = ta2 > 0.f ? ta2 : NEG * ta2;  ta3 = ta3 > 0.f ? ta3 : NEG * ta3;
    float sa = at.x * ta0 + at.y * ta1 + at.z * ta2 + at.w * ta3;
#pragma unroll
    for (int off = 1; off < 64; off <<= 1) sa += __shfl_xor(sa, off);
    float mnew = fmaxf(m, sa);
    float scale = __expf(m - mnew);
    float wa = __expf(sa - mnew);
    l = l * scale + wa;
    a0 = a0 * scale + wa * xa0;
    a1 = a1 * scale + wa * xa1;
    a2 = a2 * scale + wa * xa2;
    a3 = a3 * scale + wa * xa3;
  }
#undef LD2
  float inv = 1.f / (l + 1e-16f);
  float4 b = *(const float4*)(bias + c0);
  float4 o;
  o.x = fmaxf(a0 * inv + b.x, 0.f);
  o.y = fmaxf(a1 * inv + b.y, 0.f);
  o.z = fmaxf(a2 * inv + b.z, 0.f);
  o.w = fmaxf(a3 * inv + b.w, 0.f);
  *(float4*)(out + (long long)d * C2 + c0) = o;
}

// =============================================================================
extern "C" void kernel_launch(void* const* d_in, const int* in_sizes, int n_in,
                              void* d_out, int out_size, void* d_ws, size_t ws_size,
                              hipStream_t stream) {
  const float* x     = (const float*)d_in[0];
  const int*   ei    = (const int*)d_in[1];
  const float* W1l   = (const float*)d_in[2];
  const float* b1l   = (const float*)d_in[3];
  const float* W1r   = (const float*)d_in[4];
  const float* b1r   = (const float*)d_in[5];
  const float* att1  = (const float*)d_in[6];
  const float* bias1 = (const float*)d_in[7];
  const float* W2l   = (const float*)d_in[8];
  const float* b2l   = (const float*)d_in[9];
  const float* W2r   = (const float*)d_in[10];
  const float* b2r   = (const float*)d_in[11];
  const float* att2  = (const float*)d_in[12];
  const float* bias2 = (const float*)d_in[13];

  const int N  = in_sizes[0] / D_IN;  // 50000
  const int E0 = in_sizes[1] / 2;     // 400000
  const int E  = E0 + N;              // with self-loops
  const int Mp = (N + 255) & ~255;    // 50176 (multiple of 256)
  const int NB = (N + 255) / 256;     // scan blocks (196)

  char* p = (char*)d_ws;
  auto alloc = [&](size_t bytes) -> char* {
    char* r = p;
    p += (bytes + 255) & ~(size_t)255;
    return r;
  };
  u16* A_bf  = (u16*)alloc((size_t)Mp * D_IN * 2);   // x bf16; later X2 (layer-2 A)
  u16* XLR1  = (u16*)alloc((size_t)Mp * 2048 * 2);   // [xl|xr] layer 1; later XLR2
  u16* W1t   = (u16*)alloc((size_t)2048 * D_IN * 2);
  u16* W2t   = (u16*)alloc((size_t)512 * C1 * 2);
  float* bc1 = (float*)alloc(2048 * 4);
  float* bc2 = (float*)alloc(512 * 4);
  int* counts = (int*)alloc((size_t)N * 4);          // counts+cursor adjacent:
  int* cursor = (int*)alloc((size_t)N * 4);          //  single memset covers both
  int* indptr = (int*)alloc((size_t)(N + 1) * 4);
  int* esrc   = (int*)alloc((size_t)E * 4);
  int* bsum   = (int*)alloc((size_t)NB * 4);
  int* boff   = (int*)alloc((size_t)NB * 4);
  u16* X2   = A_bf;   // alias: A_bf dead after GEMM1
  u16* XLR2 = XLR1;   // alias: XLR1 dead after fused_edge1

  size_t need = (size_t)(p - (char*)d_ws);
  if (ws_size < need) {
    hipMemsetAsync(d_out, 0xFF, 4, stream);  // NaN sentinel
    return;
  }

  // one memset over counts..cursor (contiguous in the arena)
  hipMemsetAsync(counts, 0, (size_t)((char*)cursor - (char*)counts) + (size_t)N * 4,
                 stream);

  // ---- single prep dispatch: cast | transposes | bias | count ----
  {
    long long tot = (long long)Mp * (D_IN / 8);
    int CB = (int)((tot + 255) / 256);
    prep_all_k<<<CB + 2560 + 10 + 1024, 256, 0, stream>>>(
        x, A_bf, N, Mp, CB,
        W1l, W1r, W2l, W2r, W1t, W2t,
        b1l, b1r, b2l, b2r, bc1, bc2,
        ei, counts, E0, E);
  }

  // ---- CSR by dst (shared by both layers) ----
  blocksum_k<<<NB, 256, 0, stream>>>(counts, bsum, N);
  scanb_k<<<1, 256, 0, stream>>>(bsum, boff, NB, indptr, N, E);
  scanf_k<<<NB, 256, 0, stream>>>(counts, boff, indptr, N);
  scatter_k<<<1024, 256, 0, stream>>>(ei, indptr, cursor, esrc, E0, E);

  // ---- layer 1 ----
  gemm8_k<2048><<<dim3(Mp / 256, 2048 / 256), 512, 0, stream>>>(A_bf, W1t, bc1, XLR1, D_IN);
  fused_edge1_k<<<Mp, 256, 0, stream>>>(XLR1, indptr, esrc, att1, bias1, X2, N);

  // ---- layer 2 ----
  gemm8_k<512><<<dim3(Mp / 256, 512 / 256), 512, 0, stream>>>(X2, W2t, bc2, XLR2, C1);
  fused_edge2_k<<<(N + 3) / 4, 256, 0, stream>>>(XLR2, indptr, esrc, att2, bias2,
                                                 (float*)d_out, N);
}